// Round 10
// baseline (519.149 us; speedup 1.0000x reference)
//
#include <hip/hip_runtime.h>

// HyperbolicAttention: N=100000 nodes, C=128, H=8 heads, D=16, E=640000 edges.
// Round 10: independent-wave GEMM (wave = 32 rows x 32 cols, W-slice in regs,
//           no LDS/barrier, all loads issued up front), XCD-co-located QKV,
//           CSR-ordered scores+gather with 2-deep prefetch (round-8 form).

#define TPB 256

typedef __attribute__((ext_vector_type(8))) short short8;
typedef __attribute__((ext_vector_type(4))) short short4v;
typedef __attribute__((ext_vector_type(4))) float f32x4;

// fp32 -> bf16 round-to-nearest-even
__device__ __forceinline__ short f2bf(float f) {
    unsigned u = __float_as_uint(f);
    u += 0x7fffu + ((u >> 16) & 1u);
    return (short)(u >> 16);
}
// bf16 -> fp32
__device__ __forceinline__ float bf2f(short s) {
    return __uint_as_float(((unsigned)(unsigned short)s) << 16);
}
__device__ __forceinline__ short8 cvt8(float4 a, float4 b) {
    short8 r;
    r[0]=f2bf(a.x); r[1]=f2bf(a.y); r[2]=f2bf(a.z); r[3]=f2bf(a.w);
    r[4]=f2bf(b.x); r[5]=f2bf(b.y); r[6]=f2bf(b.z); r[7]=f2bf(b.w);
    return r;
}

// ---------------------------------------------------------------------------
// Convert the four 128x128 fp32 weight matrices to bf16 (row-major, packed).
// ---------------------------------------------------------------------------
__global__ void wconv_kernel(const float* __restrict__ W0, const float* __restrict__ W1,
                             const float* __restrict__ W2, const float* __restrict__ W3,
                             short* __restrict__ out)
{
    int i = blockIdx.x * TPB + threadIdx.x;   // 0..65535
    if (i >= 65536) return;
    const float* W = (i < 16384) ? W0 : (i < 32768) ? W1 : (i < 49152) ? W2 : W3;
    out[i] = f2bf(W[i & 16383]);
}

// ---------------------------------------------------------------------------
// Independent-wave GEMM body: Y = X @ W^T + b for one 32-row tile.
// Wave w of the block owns cols [w*32, w*32+32): its W-slice = 8 reg frags
// (no LDS, no barrier). All W + X loads issued before any use -> one memory
// round-trip per wave; then 16 MFMAs (swapped operand) + vectorized stores.
// Lane l15 = x-row, lh*4+j = output col within col-tile.
// ---------------------------------------------------------------------------
template<bool IN_BF16, bool OUT_BF16>
__device__ __forceinline__ void gemm_wave_body(
    const void* __restrict__ Xv, int nrows,
    const short* __restrict__ Wb, const float* __restrict__ bias,
    void* __restrict__ Yv, int rtile)
{
    const int tid  = threadIdx.x;
    const int wid  = tid >> 6;
    const int lane = tid & 63;
    const int l15  = lane & 15;
    const int lh   = lane >> 4;
    const int c0   = wid * 32;            // wave's column base
    const int rowbase = rtile * 32;
    const int r0 = rowbase + l15, r1 = r0 + 16;
    const bool v0 = r0 < nrows, v1 = r1 < nrows;

    // --- issue W-slice loads (8 x 16B, independent) ---
    short8 wf[2][4];
    #pragma unroll
    for (int n = 0; n < 2; ++n)
        #pragma unroll
        for (int kc = 0; kc < 4; ++kc)
            wf[n][kc] = *(const short8*)&Wb[(c0 + n*16 + l15)*128 + kc*32 + lh*8];

    // --- issue all X loads, then convert ---
    short8 xf[2][4];   // [row-group][kc]
    if (IN_BF16) {
        const short* Xb = (const short*)Xv;
        #pragma unroll
        for (int kc = 0; kc < 4; ++kc) {
            xf[0][kc] = v0 ? *(const short8*)&Xb[(size_t)r0*128 + kc*32 + lh*8]
                           : (short8)(short)0;
            xf[1][kc] = v1 ? *(const short8*)&Xb[(size_t)r1*128 + kc*32 + lh*8]
                           : (short8)(short)0;
        }
    } else {
        const float* Xf = (const float*)Xv;
        const float4* P0 = (const float4*)(Xf + (size_t)r0 * 128);
        const float4* P1 = (const float4*)(Xf + (size_t)r1 * 128);
        float4 z4 = make_float4(0.f, 0.f, 0.f, 0.f);
        float4 xa[4][2], xb[4][2];
        #pragma unroll
        for (int kc = 0; kc < 4; ++kc) {
            xa[kc][0] = v0 ? P0[kc*8 + lh*2]     : z4;
            xb[kc][0] = v0 ? P0[kc*8 + lh*2 + 1] : z4;
            xa[kc][1] = v1 ? P1[kc*8 + lh*2]     : z4;
            xb[kc][1] = v1 ? P1[kc*8 + lh*2 + 1] : z4;
        }
        #pragma unroll
        for (int kc = 0; kc < 4; ++kc) {
            xf[0][kc] = cvt8(xa[kc][0], xb[kc][0]);
            xf[1][kc] = cvt8(xa[kc][1], xb[kc][1]);
        }
    }

    // --- MFMA burst: 2 col-tiles x 2 row-groups x 4 kc ---
    f32x4 acc[2][2];   // [n][g]
    #pragma unroll
    for (int n = 0; n < 2; ++n) { acc[n][0] = (f32x4)0.f; acc[n][1] = (f32x4)0.f; }

    #pragma unroll
    for (int kc = 0; kc < 4; ++kc)
        #pragma unroll
        for (int n = 0; n < 2; ++n) {
            acc[n][0] = __builtin_amdgcn_mfma_f32_16x16x32_bf16(wf[n][kc], xf[0][kc], acc[n][0], 0, 0, 0);
            acc[n][1] = __builtin_amdgcn_mfma_f32_16x16x32_bf16(wf[n][kc], xf[1][kc], acc[n][1], 0, 0, 0);
        }

    // --- epilogue: vectorized stores ---
    #pragma unroll
    for (int g = 0; g < 2; ++g) {
        int row = rowbase + g*16 + l15;
        if (row >= nrows) continue;
        #pragma unroll
        for (int n = 0; n < 2; ++n) {
            float4 b4 = *(const float4*)&bias[c0 + n*16 + lh*4];
            float y0 = acc[n][g][0] + b4.x;
            float y1 = acc[n][g][1] + b4.y;
            float y2 = acc[n][g][2] + b4.z;
            float y3 = acc[n][g][3] + b4.w;
            if (OUT_BF16) {
                short4v s; s[0]=f2bf(y0); s[1]=f2bf(y1); s[2]=f2bf(y2); s[3]=f2bf(y3);
                *(short4v*)&((short*)Yv)[(size_t)row * 128 + c0 + n*16 + lh*4] = s;
            } else {
                *(float4*)&((float*)Yv)[(size_t)row * 128 + c0 + n*16 + lh*4] =
                    make_float4(y0, y1, y2, y3);
            }
        }
    }
}

// Fused QKV with XCD co-location (round-8 mapping, 32-row tiles):
// b -> k=b&7, j=b>>3, w=j%3, x=k+8*(j/3); slices of one tile share b%8.
__global__ __launch_bounds__(256) void gemm_qkv_kernel(
    const float* __restrict__ X, int nrows, int nxblk,
    const short* __restrict__ WB,
    const float* __restrict__ bq, const float* __restrict__ bk,
    const float* __restrict__ bv,
    short* __restrict__ Yb, size_t slice)
{
    int b = blockIdx.x;
    int k = b & 7, j = b >> 3;
    int jd = j / 3, w = j - 3 * jd;
    int x = k + 8 * jd;
    if (x >= nxblk) return;
    const float* bias = (w == 0) ? bq : (w == 1) ? bk : bv;
    gemm_wave_body<false, true>(X, nrows, WB + w * 16384, bias,
                                Yb + (size_t)w * slice, x);
}

// Output projection: bf16 in, fp32 out.
__global__ __launch_bounds__(256) void gemm_out_kernel(
    const short* __restrict__ Xb, int nrows,
    const short* __restrict__ Wb, const float* __restrict__ bias,
    float* __restrict__ Y)
{
    gemm_wave_body<true, false>(Xb, nrows, Wb, bias, Y, blockIdx.x);
}

// ---------------------------------------------------------------------------
// edge_index may arrive as int64 (reference) or int32. Detect on device.
// ---------------------------------------------------------------------------
__global__ void detect_i64_kernel(const int* __restrict__ raw, int* __restrict__ flag)
{
    if (blockIdx.x == 0 && threadIdx.x == 0) {
        int odd_nonzero = 0;
        for (int i = 0; i < 128; ++i)
            if (raw[2 * i + 1] != 0) odd_nonzero = 1;
        *flag = odd_nonzero ? 0 : 1;  // 1 => int64 layout
    }
}

// Convert to int32; simultaneously histogram destination rows (i < E).
__global__ void conv_hist_kernel(const void* __restrict__ raw, int E,
                                 const int* __restrict__ flag,
                                 int* __restrict__ out, int* __restrict__ deg)
{
    int i = blockIdx.x * TPB + threadIdx.x;
    if (i >= 2 * E) return;
    int v;
    if (*flag) v = (int)((const long long*)raw)[i];
    else       v = ((const int*)raw)[i];
    out[i] = v;
    if (i < E) atomicAdd(&deg[v], 1);
}

// ---------------------------------------------------------------------------
// CSR scan: block-local exclusive scan, block-sum scan, add-back (also
// initializes cursor = rowstart).
// ---------------------------------------------------------------------------
__global__ void scan1_kernel(const int* __restrict__ deg, int n,
                             int* __restrict__ rowstart, int* __restrict__ bsum)
{
    __shared__ int sm[TPB];
    int t = threadIdx.x;
    int gid = blockIdx.x * TPB + t;
    int v = (gid < n) ? deg[gid] : 0;
    sm[t] = v;
    __syncthreads();
    for (int off = 1; off < TPB; off <<= 1) {
        int x = (t >= off) ? sm[t - off] : 0;
        __syncthreads();
        sm[t] += x;
        __syncthreads();
    }
    if (gid < n) rowstart[gid] = sm[t] - v;
    if (t == TPB - 1) bsum[blockIdx.x] = sm[t];
}

__global__ void scan2_kernel(int* __restrict__ bsum, int nb)
{
    __shared__ int sm[512];
    int t = threadIdx.x;
    int v = (t < nb) ? bsum[t] : 0;
    sm[t] = v;
    __syncthreads();
    for (int off = 1; off < 512; off <<= 1) {
        int x = (t >= off) ? sm[t - off] : 0;
        __syncthreads();
        sm[t] += x;
        __syncthreads();
    }
    if (t < nb) bsum[t] = sm[t] - v;
}

__global__ void scan3_kernel(int* __restrict__ rowstart, int* __restrict__ cursor,
                             int n, int E, const int* __restrict__ bsum)
{
    int gid = blockIdx.x * TPB + threadIdx.x;
    if (gid < n) {
        int v = rowstart[gid] + bsum[blockIdx.x];
        rowstart[gid] = v;
        cursor[gid] = v;
    }
    if (gid == 0) rowstart[n] = E;
}

// Bin edges by destination: ecol[p] = col of edge, p in the dest's segment.
__global__ void fill_kernel(const int* __restrict__ ei, int E,
                            int* __restrict__ cursor, int* __restrict__ ecol)
{
    int e = blockIdx.x * TPB + threadIdx.x;
    if (e >= E) return;
    int pos = atomicAdd(&cursor[ei[e]], 1);
    ecol[pos] = ei[E + e];
}

// ---------------------------------------------------------------------------
// CSR-ordered scores + fused online softmax partials, 2-deep prefetch.
// thread = (node, h): Q slice in regs; K rows shared by the node's 8 lanes;
// S written sequentially at [p*8+h].
// ---------------------------------------------------------------------------
__global__ __launch_bounds__(256) void csr_score_stats_kernel(
    const short* __restrict__ Qb, const short* __restrict__ Kb,
    const int* __restrict__ ecol, const int* __restrict__ rowstart, int N,
    float* __restrict__ S, float* __restrict__ mpart, float* __restrict__ zpart)
{
    int t = threadIdx.x;
    int idx = blockIdx.x * TPB + t;
    float m = -3.0e38f, z = 0.f;
    if (idx < N * 8) {
        int node = idx >> 3, h = idx & 7;
        const short8* q8 = (const short8*)(Qb + (size_t)node * 128 + h * 16);
        short8 q0 = q8[0], q1 = q8[1];
        int p0 = rowstart[node], p1 = rowstart[node + 1];
        if (p0 < p1) {
            const short8* kc = (const short8*)(Kb + (size_t)ecol[p0] * 128 + h * 16);
            short8 k0 = kc[0], k1 = kc[1];
            for (int p = p0; p < p1; ++p) {
                short8 k0n = k0, k1n = k1;
                if (p + 1 < p1) {
                    const short8* kn = (const short8*)(Kb + (size_t)ecol[p+1] * 128 + h * 16);
                    k0n = kn[0]; k1n = kn[1];
                }
                float dot = 0.f;
                #pragma unroll
                for (int i = 0; i < 8; ++i) {
                    dot += bf2f(q0[i]) * bf2f(k0[i]);
                    dot += bf2f(q1[i]) * bf2f(k1[i]);
                }
                float s = dot * 0.25f;  // 1/sqrt(16)
                S[(size_t)p * 8 + h] = s;
                float M = fmaxf(m, s);
                z = z * __expf(m - M) + __expf(s - M);
                m = M;
                k0 = k0n; k1 = k1n;
            }
        }
    }
    __shared__ float sm[TPB], sz[TPB];
    sm[t] = m; sz[t] = z;
    __syncthreads();
    for (int off = 128; off >= 8; off >>= 1) {
        if (t < off) {
            float m2 = sm[t + off], z2 = sz[t + off];
            float M = fmaxf(sm[t], m2);
            sz[t] = sz[t] * __expf(sm[t] - M) + z2 * __expf(m2 - M);
            sm[t] = M;
        }
        __syncthreads();
    }
    if (t < 8) {
        mpart[blockIdx.x * 8 + t] = sm[t];
        zpart[blockIdx.x * 8 + t] = sz[t];
    }
}

// One block: combine nb per-block partials -> MZ[h] (max), MZ[8+h] (Z).
__global__ void stats_reduce_kernel(const float* __restrict__ mpart,
                                    const float* __restrict__ zpart,
                                    int nb, float* __restrict__ MZ)
{
    int t = threadIdx.x;
    int h = t & 7, chunk = t >> 3;   // 32 chunks
    float m = -3.0e38f, z = 0.f;
    for (int i = chunk; i < nb; i += 32) {
        float m2 = mpart[i * 8 + h], z2 = zpart[i * 8 + h];
        float M = fmaxf(m, m2);
        z = z * __expf(m - M) + z2 * __expf(m2 - M);
        m = M;
    }
    __shared__ float sm[TPB], sz[TPB];
    sm[t] = m; sz[t] = z;
    __syncthreads();
    for (int off = 128; off >= 8; off >>= 1) {
        if (t < off) {
            float m2 = sm[t + off], z2 = sz[t + off];
            float M = fmaxf(sm[t], m2);
            sz[t] = sz[t] * __expf(sm[t] - M) + z2 * __expf(m2 - M);
            sm[t] = M;
        }
        __syncthreads();
    }
    if (t < 8) { MZ[t] = sm[t]; MZ[8 + t] = sz[t]; }
}

// ---------------------------------------------------------------------------
// Gather segment-sum, fused exp/normalize, 2-deep prefetch.
// thread = (node, head); S sequential; V rows shared by the node's 8 lanes.
// ---------------------------------------------------------------------------
__global__ __launch_bounds__(256) void gather_kernel(
    const float* __restrict__ S, const short* __restrict__ Vb,
    const int* __restrict__ ecol,
    const int* __restrict__ rowstart,
    const float* __restrict__ MZ, int N,
    short* __restrict__ outb)
{
    int idx = blockIdx.x * TPB + threadIdx.x;
    if (idx >= N * 8) return;
    int node = idx >> 3, h = idx & 7;
    float M = MZ[h];
    float invZ = 1.0f / MZ[8 + h];
    int p0 = rowstart[node], p1 = rowstart[node + 1];

    float a[16];
    #pragma unroll
    for (int i = 0; i < 16; ++i) a[i] = 0.f;

    if (p0 < p1) {
        const short8* vc = (const short8*)(Vb + (size_t)ecol[p0] * 128 + h * 16);
        short8 v0 = vc[0], v1 = vc[1];
        float sc = S[(size_t)p0 * 8 + h];
        for (int p = p0; p < p1; ++p) {
            short8 v0n = v0, v1n = v1;
            float sn = sc;
            if (p + 1 < p1) {
                const short8* vn = (const short8*)(Vb + (size_t)ecol[p+1] * 128 + h * 16);
                v0n = vn[0]; v1n = vn[1];
                sn = S[(size_t)(p+1) * 8 + h];
            }
            float w = __expf(sc - M) * invZ;
            #pragma unroll
            for (int i = 0; i < 8; ++i) {
                a[i]     += w * bf2f(v0[i]);
                a[8 + i] += w * bf2f(v1[i]);
            }
            v0 = v0n; v1 = v1n; sc = sn;
        }
    }
    short8 o0, o1;
    #pragma unroll
    for (int i = 0; i < 8; ++i) { o0[i] = f2bf(a[i]); o1[i] = f2bf(a[8 + i]); }
    short8* ob = (short8*)(outb + (size_t)node * 128 + h * 16);
    ob[0] = o0; ob[1] = o1;
}

// ---------------------------------------------------------------------------
extern "C" void kernel_launch(void* const* d_in, const int* in_sizes, int n_in,
                              void* d_out, int out_size, void* d_ws, size_t ws_size,
                              hipStream_t stream)
{
    const float* feat = (const float*)d_in[0];
    const void*  eraw = d_in[1];
    const float* Wq = (const float*)d_in[2];
    const float* bq = (const float*)d_in[3];
    const float* Wk = (const float*)d_in[4];
    const float* bk = (const float*)d_in[5];
    const float* Wv = (const float*)d_in[6];
    const float* bv = (const float*)d_in[7];
    const float* Wo = (const float*)d_in[8];
    const float* bo = (const float*)d_in[9];

    const int N = in_sizes[0] / 128;
    const int E = in_sizes[1] / 2;
    const size_t NC = (size_t)N * 128;
    const int EH = E * 8;
    const int gbN = (N * 8 + TPB - 1) / TPB;   // node-head grid (scores/gather)

    // Workspace layout
    short* Qb   = (short*)d_ws;            // [N][128] bf16 (Q,K,V contiguous)
    short* Kb   = Qb + NC;
    short* Vb   = Kb + NC;
    short* ACCb = Vb + NC;                 // [N][128] bf16
    float* S    = (float*)(ACCb + NC);     // [E*8] scores, CSR order
    int*   EI   = (int*)(S + EH);          // int32 indices, 2*E
    short* WB   = (short*)(EI + 2 * E);    // 4 x 16384 bf16 weights
    float* mpart = (float*)(WB + 65536);   // [gbN][8]
    float* zpart = mpart + (size_t)gbN * 8;
    float* MZ    = zpart + (size_t)gbN * 8; // 16: M[8], Z[8]
    int*   flag  = (int*)(MZ + 16);
    int* deg      = flag + 16;             // N
    int* rowstart = deg + N;               // N+1
    int* cursor   = rowstart + N + 1;      // N
    int* bsum     = cursor + N;            // 512
    int* ecol     = bsum + 512;            // E (binned cols)

    const int nbS = (N + TPB - 1) / TPB;
    const int ebE = (E + TPB - 1) / TPB;

    // --- CSR build (independent of GEMMs) ---
    hipMemsetAsync(deg, 0, (size_t)N * sizeof(int), stream);
    detect_i64_kernel<<<1, 64, 0, stream>>>((const int*)eraw, flag);
    conv_hist_kernel<<<(2 * E + TPB - 1) / TPB, TPB, 0, stream>>>(eraw, E, flag, EI, deg);
    scan1_kernel<<<nbS, TPB, 0, stream>>>(deg, N, rowstart, bsum);
    scan2_kernel<<<1, 512, 0, stream>>>(bsum, nbS);
    scan3_kernel<<<nbS, TPB, 0, stream>>>(rowstart, cursor, N, E, bsum);
    fill_kernel<<<ebE, TPB, 0, stream>>>(EI, E, cursor, ecol);

    // --- Projections ---
    wconv_kernel<<<256, TPB, 0, stream>>>(Wq, Wk, Wv, Wo, WB);
    const int nxblk = (N + 31) / 32;                   // 32-row tiles (3125)
    const int qkvgrid = 8 * 3 * ((nxblk + 7) / 8);     // XCD-co-located mapping
    gemm_qkv_kernel<<<qkvgrid, TPB, 0, stream>>>(feat, N, nxblk, WB, bq, bk, bv, Qb, NC);

    // --- Scores + softmax stats (CSR order) ---
    csr_score_stats_kernel<<<gbN, TPB, 0, stream>>>(Qb, Kb, ecol, rowstart, N,
                                                    S, mpart, zpart);
    stats_reduce_kernel<<<1, TPB, 0, stream>>>(mpart, zpart, gbN, MZ);

    // --- Gather segment-sum with fused exp/normalize -> bf16 ACC ---
    gather_kernel<<<gbN, TPB, 0, stream>>>(S, Vb, ecol, rowstart, MZ, N, ACCb);

    // --- Output projection (bf16 in, fp32 out) ---
    gemm_out_kernel<<<nxblk, TPB, 0, stream>>>(ACCb, N, WB + 3 * 16384, bo, (float*)d_out);
}

// Round 11
// 299.313 us; speedup vs baseline: 1.7345x; 1.7345x over previous
//
#include <hip/hip_runtime.h>

// HyperbolicAttention: N=100000 nodes, C=128, H=8 heads, D=16, E=640000 edges.
// Round 11: GEMM reverted to round-8 structure (one-shot 128-row blocks, LDS W,
//           up-front loads, XCD co-located QKV). Scores+gather FUSED into one
//           flash-style CSR pass (online m,z,o per node-head); softmax scale
//           folded into the out-GEMM A-frag load.

#define TPB 256

typedef __attribute__((ext_vector_type(8))) short short8;
typedef __attribute__((ext_vector_type(4))) short short4v;
typedef __attribute__((ext_vector_type(4))) float f32x4;

// fp32 -> bf16 round-to-nearest-even
__device__ __forceinline__ short f2bf(float f) {
    unsigned u = __float_as_uint(f);
    u += 0x7fffu + ((u >> 16) & 1u);
    return (short)(u >> 16);
}
// bf16 -> fp32
__device__ __forceinline__ float bf2f(short s) {
    return __uint_as_float(((unsigned)(unsigned short)s) << 16);
}

// ---------------------------------------------------------------------------
// Convert the four 128x128 fp32 weight matrices to bf16 (row-major, packed).
// ---------------------------------------------------------------------------
__global__ void wconv_kernel(const float* __restrict__ W0, const float* __restrict__ W1,
                             const float* __restrict__ W2, const float* __restrict__ W3,
                             short* __restrict__ out)
{
    int i = blockIdx.x * TPB + threadIdx.x;   // 0..65535
    if (i >= 65536) return;
    const float* W = (i < 16384) ? W0 : (i < 32768) ? W1 : (i < 49152) ? W2 : W3;
    out[i] = f2bf(W[i & 16383]);
}

// ---------------------------------------------------------------------------
// Round-8 GEMM body (proven 58us for QKV): one 128-row tile per block; all
// global loads (8 W-frags + 16 X-float4) issued before any wait; W -> LDS
// frag-major; swapped-operand MFMA; vectorized stores.
// ---------------------------------------------------------------------------
__device__ __forceinline__ void gemm_body_f32in_bf16out(
    const float* __restrict__ X, int nrows,
    const short* __restrict__ Wb, const float* __restrict__ bias,
    short* __restrict__ Yb, int xblk)
{
    __shared__ short lw[16384];   // 32 KiB W, frag-major
    const int tid = threadIdx.x;

    // --- issue W global loads (8 x 16B per thread) ---
    short8 wreg[8];
    #pragma unroll
    for (int r = 0; r < 8; ++r) {
        int c = r * 256 + tid;              // chunk id 0..2047
        int fragid = c >> 6, ln = c & 63;
        int n = fragid >> 2, kc = fragid & 3;
        wreg[r] = *(const short8*)&Wb[(n*16 + (ln & 15))*128 + kc*32 + (ln >> 4)*8];
    }

    const int wid = tid >> 6;
    const int lane = tid & 63;
    const int l15 = lane & 15;
    const int lh  = lane >> 4;
    const int rowbase = xblk * 128 + wid * 32;
    const int r0 = rowbase + l15, r1 = r0 + 16;
    const bool vv0 = r0 < nrows, vv1 = r1 < nrows;

    // --- issue ALL X loads, then convert ---
    const float4* P0 = (const float4*)(X + (size_t)r0 * 128);
    const float4* P1 = (const float4*)(X + (size_t)r1 * 128);
    float4 z4 = make_float4(0.f, 0.f, 0.f, 0.f);
    float4 xa[4][2], xb[4][2];
    #pragma unroll
    for (int kc = 0; kc < 4; ++kc) {
        xa[kc][0] = vv0 ? P0[kc*8 + lh*2]     : z4;
        xb[kc][0] = vv0 ? P0[kc*8 + lh*2 + 1] : z4;
        xa[kc][1] = vv1 ? P1[kc*8 + lh*2]     : z4;
        xb[kc][1] = vv1 ? P1[kc*8 + lh*2 + 1] : z4;
    }
    short8 xfr[4][2];
    #pragma unroll
    for (int kc = 0; kc < 4; ++kc)
        #pragma unroll
        for (int g = 0; g < 2; ++g) {
            xfr[kc][g][0] = f2bf(xa[kc][g].x);
            xfr[kc][g][1] = f2bf(xa[kc][g].y);
            xfr[kc][g][2] = f2bf(xa[kc][g].z);
            xfr[kc][g][3] = f2bf(xa[kc][g].w);
            xfr[kc][g][4] = f2bf(xb[kc][g].x);
            xfr[kc][g][5] = f2bf(xb[kc][g].y);
            xfr[kc][g][6] = f2bf(xb[kc][g].z);
            xfr[kc][g][7] = f2bf(xb[kc][g].w);
        }

    // --- W regs -> LDS, barrier ---
    #pragma unroll
    for (int r = 0; r < 8; ++r)
        *(short8*)&lw[(r * 256 + tid) * 8] = wreg[r];
    __syncthreads();

    // --- pure LDS + MFMA loop ---
    f32x4 acc[8][2];
    #pragma unroll
    for (int n = 0; n < 8; ++n) { acc[n][0] = (f32x4)0.f; acc[n][1] = (f32x4)0.f; }

    #pragma unroll
    for (int kc = 0; kc < 4; ++kc) {
        short8 wf[8];
        #pragma unroll
        for (int n = 0; n < 8; ++n)
            wf[n] = *(const short8*)&lw[((n*4 + kc)*64 + lane) * 8];
        #pragma unroll
        for (int n = 0; n < 8; ++n) {
            acc[n][0] = __builtin_amdgcn_mfma_f32_16x16x32_bf16(wf[n], xfr[kc][0], acc[n][0], 0, 0, 0);
            acc[n][1] = __builtin_amdgcn_mfma_f32_16x16x32_bf16(wf[n], xfr[kc][1], acc[n][1], 0, 0, 0);
        }
    }

    // --- epilogue: bf16 row-major ---
    #pragma unroll
    for (int g = 0; g < 2; ++g) {
        int row = rowbase + g*16 + l15;
        if (row >= nrows) continue;
        #pragma unroll
        for (int n = 0; n < 8; ++n) {
            float4 b4 = *(const float4*)&bias[n*16 + lh*4];
            short4v s;
            s[0] = f2bf(acc[n][g][0] + b4.x);
            s[1] = f2bf(acc[n][g][1] + b4.y);
            s[2] = f2bf(acc[n][g][2] + b4.z);
            s[3] = f2bf(acc[n][g][3] + b4.w);
            *(short4v*)&Yb[(size_t)row * 128 + n*16 + lh*4] = s;
        }
    }
}

// Fused QKV with XCD co-location (round-8 mapping): the 3 W-slices of X-tile x
// map to b = (x&7) + 8*(3*(x>>3) + w) -> share b%8 (same XCD), time-aligned.
__global__ __launch_bounds__(256) void gemm_qkv_kernel(
    const float* __restrict__ X, int nrows, int nxblk,
    const short* __restrict__ WB,
    const float* __restrict__ bq, const float* __restrict__ bk,
    const float* __restrict__ bv,
    short* __restrict__ Yb, size_t slice)
{
    int b = blockIdx.x;
    int k = b & 7, j = b >> 3;
    int jd = j / 3, w = j - 3 * jd;
    int x = k + 8 * jd;
    if (x >= nxblk) return;
    const float* bias = (w == 0) ? bq : (w == 1) ? bk : bv;
    gemm_body_f32in_bf16out(X, nrows, WB + w * 16384, bias,
                            Yb + (size_t)w * slice, x);
}

// ---------------------------------------------------------------------------
// Output projection with folded softmax scale: A[row][col] = bf2f(Ob) * sc[row, head(col)],
// where head(col) = col>>4. bf16-in + per-(row,head) fp32 scale, fp32 out.
// Same one-shot structure as gemm_body (LDS W, up-front loads).
// ---------------------------------------------------------------------------
__global__ __launch_bounds__(256) void gemm_out_kernel(
    const short* __restrict__ Xb, const float* __restrict__ sc, int nrows,
    const short* __restrict__ Wb, const float* __restrict__ bias,
    float* __restrict__ Y)
{
    __shared__ short lw[16384];
    const int tid = threadIdx.x;

    short8 wreg[8];
    #pragma unroll
    for (int r = 0; r < 8; ++r) {
        int c = r * 256 + tid;
        int fragid = c >> 6, ln = c & 63;
        int n = fragid >> 2, kc = fragid & 3;
        wreg[r] = *(const short8*)&Wb[(n*16 + (ln & 15))*128 + kc*32 + (ln >> 4)*8];
    }

    const int wid = tid >> 6;
    const int lane = tid & 63;
    const int l15 = lane & 15;
    const int lh  = lane >> 4;
    const int rowbase = blockIdx.x * 128 + wid * 32;
    const int r0 = rowbase + l15, r1 = r0 + 16;
    const bool vv0 = r0 < nrows, vv1 = r1 < nrows;

    // Raw A loads + per-(row,head) scale loads, all issued up front.
    short8 xraw[4][2];
    float  s0[4], s1[4];
    #pragma unroll
    for (int kc = 0; kc < 4; ++kc) {
        xraw[kc][0] = vv0 ? *(const short8*)&Xb[(size_t)r0*128 + kc*32 + lh*8]
                          : (short8)(short)0;
        xraw[kc][1] = vv1 ? *(const short8*)&Xb[(size_t)r1*128 + kc*32 + lh*8]
                          : (short8)(short)0;
        int h = kc*2 + (lh >> 1);          // head of cols kc*32+lh*8 .. +7
        s0[kc] = vv0 ? sc[(size_t)r0*8 + h] : 0.f;
        s1[kc] = vv1 ? sc[(size_t)r1*8 + h] : 0.f;
    }
    short8 xfr[4][2];
    #pragma unroll
    for (int kc = 0; kc < 4; ++kc)
        #pragma unroll
        for (int i = 0; i < 8; ++i) {
            xfr[kc][0][i] = f2bf(bf2f(xraw[kc][0][i]) * s0[kc]);
            xfr[kc][1][i] = f2bf(bf2f(xraw[kc][1][i]) * s1[kc]);
        }

    #pragma unroll
    for (int r = 0; r < 8; ++r)
        *(short8*)&lw[(r * 256 + tid) * 8] = wreg[r];
    __syncthreads();

    f32x4 acc[8][2];
    #pragma unroll
    for (int n = 0; n < 8; ++n) { acc[n][0] = (f32x4)0.f; acc[n][1] = (f32x4)0.f; }

    #pragma unroll
    for (int kc = 0; kc < 4; ++kc) {
        short8 wf[8];
        #pragma unroll
        for (int n = 0; n < 8; ++n)
            wf[n] = *(const short8*)&lw[((n*4 + kc)*64 + lane) * 8];
        #pragma unroll
        for (int n = 0; n < 8; ++n) {
            acc[n][0] = __builtin_amdgcn_mfma_f32_16x16x32_bf16(wf[n], xfr[kc][0], acc[n][0], 0, 0, 0);
            acc[n][1] = __builtin_amdgcn_mfma_f32_16x16x32_bf16(wf[n], xfr[kc][1], acc[n][1], 0, 0, 0);
        }
    }

    #pragma unroll
    for (int g = 0; g < 2; ++g) {
        int row = rowbase + g*16 + l15;
        if (row >= nrows) continue;
        #pragma unroll
        for (int n = 0; n < 8; ++n) {
            float4 b4 = *(const float4*)&bias[n*16 + lh*4];
            *(float4*)&Y[(size_t)row * 128 + n*16 + lh*4] =
                make_float4(acc[n][g][0] + b4.x, acc[n][g][1] + b4.y,
                            acc[n][g][2] + b4.z, acc[n][g][3] + b4.w);
        }
    }
}

// ---------------------------------------------------------------------------
// edge_index may arrive as int64 (reference) or int32. Detect on device.
// ---------------------------------------------------------------------------
__global__ void detect_i64_kernel(const int* __restrict__ raw, int* __restrict__ flag)
{
    if (blockIdx.x == 0 && threadIdx.x == 0) {
        int odd_nonzero = 0;
        for (int i = 0; i < 128; ++i)
            if (raw[2 * i + 1] != 0) odd_nonzero = 1;
        *flag = odd_nonzero ? 0 : 1;  // 1 => int64 layout
    }
}

// Convert to int32; simultaneously histogram destination rows (i < E).
__global__ void conv_hist_kernel(const void* __restrict__ raw, int E,
                                 const int* __restrict__ flag,
                                 int* __restrict__ out, int* __restrict__ deg)
{
    int i = blockIdx.x * TPB + threadIdx.x;
    if (i >= 2 * E) return;
    int v;
    if (*flag) v = (int)((const long long*)raw)[i];
    else       v = ((const int*)raw)[i];
    out[i] = v;
    if (i < E) atomicAdd(&deg[v], 1);
}

// ---------------------------------------------------------------------------
// CSR scan chain.
// ---------------------------------------------------------------------------
__global__ void scan1_kernel(const int* __restrict__ deg, int n,
                             int* __restrict__ rowstart, int* __restrict__ bsum)
{
    __shared__ int sm[TPB];
    int t = threadIdx.x;
    int gid = blockIdx.x * TPB + t;
    int v = (gid < n) ? deg[gid] : 0;
    sm[t] = v;
    __syncthreads();
    for (int off = 1; off < TPB; off <<= 1) {
        int x = (t >= off) ? sm[t - off] : 0;
        __syncthreads();
        sm[t] += x;
        __syncthreads();
    }
    if (gid < n) rowstart[gid] = sm[t] - v;
    if (t == TPB - 1) bsum[blockIdx.x] = sm[t];
}

__global__ void scan2_kernel(int* __restrict__ bsum, int nb)
{
    __shared__ int sm[512];
    int t = threadIdx.x;
    int v = (t < nb) ? bsum[t] : 0;
    sm[t] = v;
    __syncthreads();
    for (int off = 1; off < 512; off <<= 1) {
        int x = (t >= off) ? sm[t - off] : 0;
        __syncthreads();
        sm[t] += x;
        __syncthreads();
    }
    if (t < nb) bsum[t] = sm[t] - v;
}

__global__ void scan3_kernel(int* __restrict__ rowstart, int* __restrict__ cursor,
                             int n, int E, const int* __restrict__ bsum)
{
    int gid = blockIdx.x * TPB + threadIdx.x;
    if (gid < n) {
        int v = rowstart[gid] + bsum[blockIdx.x];
        rowstart[gid] = v;
        cursor[gid] = v;
    }
    if (gid == 0) rowstart[n] = E;
}

// Bin edges by destination: ecol[p] = col of edge, p in the dest's segment.
__global__ void fill_kernel(const int* __restrict__ ei, int E,
                            int* __restrict__ cursor, int* __restrict__ ecol)
{
    int e = blockIdx.x * TPB + threadIdx.x;
    if (e >= E) return;
    int pos = atomicAdd(&cursor[ei[e]], 1);
    ecol[pos] = ei[E + e];
}

// ---------------------------------------------------------------------------
// Fused flash-style edge pass: thread = (node, head).
// Online m,z,o over the node's edges; K and V rows loaded once per edge
// (shared by the node's 8 lanes); 2-deep prefetch.
// Writes o (bf16, pre-normalization) + m_loc; per-block (m,z) partials.
// ---------------------------------------------------------------------------
__global__ __launch_bounds__(256) void flash_edge_kernel(
    const short* __restrict__ Qb, const short* __restrict__ Kb,
    const short* __restrict__ Vb,
    const int* __restrict__ ecol, const int* __restrict__ rowstart, int N,
    short* __restrict__ Ob, float* __restrict__ mloc,
    float* __restrict__ mpart, float* __restrict__ zpart)
{
    int t = threadIdx.x;
    int idx = blockIdx.x * TPB + t;
    float m = -3.0e38f, z = 0.f;
    if (idx < N * 8) {
        int node = idx >> 3, h = idx & 7;
        const short8* q8 = (const short8*)(Qb + (size_t)node * 128 + h * 16);
        short8 q0 = q8[0], q1 = q8[1];
        int p0 = rowstart[node], p1 = rowstart[node + 1];

        float o[16];
        #pragma unroll
        for (int i = 0; i < 16; ++i) o[i] = 0.f;

        if (p0 < p1) {
            int c = ecol[p0];
            const short8* kp = (const short8*)(Kb + (size_t)c * 128 + h * 16);
            const short8* vp = (const short8*)(Vb + (size_t)c * 128 + h * 16);
            short8 k0 = kp[0], k1 = kp[1], v0 = vp[0], v1 = vp[1];

            for (int p = p0; p < p1; ++p) {
                short8 k0n = k0, k1n = k1, v0n = v0, v1n = v1;
                if (p + 1 < p1) {
                    int cn = ecol[p + 1];
                    const short8* kn = (const short8*)(Kb + (size_t)cn * 128 + h * 16);
                    const short8* vn = (const short8*)(Vb + (size_t)cn * 128 + h * 16);
                    k0n = kn[0]; k1n = kn[1]; v0n = vn[0]; v1n = vn[1];
                }
                float dot = 0.f;
                #pragma unroll
                for (int i = 0; i < 8; ++i) {
                    dot += bf2f(q0[i]) * bf2f(k0[i]);
                    dot += bf2f(q1[i]) * bf2f(k1[i]);
                }
                float s = dot * 0.25f;   // 1/sqrt(16)

                float e;
                if (s > m) {
                    float scl = __expf(m - s);
                    z *= scl;
                    #pragma unroll
                    for (int i = 0; i < 16; ++i) o[i] *= scl;
                    m = s;
                    e = 1.f;
                } else {
                    e = __expf(s - m);
                }
                z += e;
                #pragma unroll
                for (int i = 0; i < 8; ++i) {
                    o[i]     += e * bf2f(v0[i]);
                    o[8 + i] += e * bf2f(v1[i]);
                }
                k0 = k0n; k1 = k1n; v0 = v0n; v1 = v1n;
            }
        }

        short8 o0, o1;
        #pragma unroll
        for (int i = 0; i < 8; ++i) { o0[i] = f2bf(o[i]); o1[i] = f2bf(o[8 + i]); }
        short8* ob = (short8*)(Ob + (size_t)node * 128 + h * 16);
        ob[0] = o0; ob[1] = o1;
        mloc[idx] = m;
    }

    // Per-block online (m,z) partials per head (head class = t&7 invariant).
    __shared__ float sm[TPB], sz[TPB];
    sm[t] = m; sz[t] = z;
    __syncthreads();
    for (int off = 128; off >= 8; off >>= 1) {
        if (t < off) {
            float m2 = sm[t + off], z2 = sz[t + off];
            float M = fmaxf(sm[t], m2);
            sz[t] = sz[t] * __expf(sm[t] - M) + z2 * __expf(m2 - M);
            sm[t] = M;
        }
        __syncthreads();
    }
    if (t < 8) {
        mpart[blockIdx.x * 8 + t] = sm[t];
        zpart[blockIdx.x * 8 + t] = sz[t];
    }
}

// One block: combine nb per-block partials -> MZ[h] (max), MZ[8+h] (Z).
__global__ void stats_reduce_kernel(const float* __restrict__ mpart,
                                    const float* __restrict__ zpart,
                                    int nb, float* __restrict__ MZ)
{
    int t = threadIdx.x;
    int h = t & 7, chunk = t >> 3;   // 32 chunks
    float m = -3.0e38f, z = 0.f;
    for (int i = chunk; i < nb; i += 32) {
        float m2 = mpart[i * 8 + h], z2 = zpart[i * 8 + h];
        float M = fmaxf(m, m2);
        z = z * __expf(m - M) + z2 * __expf(m2 - M);
        m = M;
    }
    __shared__ float sm[TPB], sz[TPB];
    sm[t] = m; sz[t] = z;
    __syncthreads();
    for (int off = 128; off >= 8; off >>= 1) {
        if (t < off) {
            float m2 = sm[t + off], z2 = sz[t + off];
            float M = fmaxf(sm[t], m2);
            sz[t] = sz[t] * __expf(sm[t] - M) + z2 * __expf(m2 - M);
            sm[t] = M;
        }
        __syncthreads();
    }
    if (t < 8) { MZ[t] = sm[t]; MZ[8 + t] = sz[t]; }
}

// sc[node*8+h] = exp(mloc - M[h]) / Z[h]  (deg-0: exp(-3e38-M) -> 0)
__global__ void scale_prep_kernel(const float* __restrict__ mloc,
                                  const float* __restrict__ MZ, int total,
                                  float* __restrict__ sc)
{
    int idx = blockIdx.x * TPB + threadIdx.x;
    if (idx >= total) return;
    int h = idx & 7;
    sc[idx] = __expf(mloc[idx] - MZ[h]) / MZ[8 + h];
}

// ---------------------------------------------------------------------------
extern "C" void kernel_launch(void* const* d_in, const int* in_sizes, int n_in,
                              void* d_out, int out_size, void* d_ws, size_t ws_size,
                              hipStream_t stream)
{
    const float* feat = (const float*)d_in[0];
    const void*  eraw = d_in[1];
    const float* Wq = (const float*)d_in[2];
    const float* bq = (const float*)d_in[3];
    const float* Wk = (const float*)d_in[4];
    const float* bk = (const float*)d_in[5];
    const float* Wv = (const float*)d_in[6];
    const float* bv = (const float*)d_in[7];
    const float* Wo = (const float*)d_in[8];
    const float* bo = (const float*)d_in[9];

    const int N = in_sizes[0] / 128;
    const int E = in_sizes[1] / 2;
    const size_t NC = (size_t)N * 128;
    const int gbN = (N * 8 + TPB - 1) / TPB;   // node-head grid

    // Workspace layout
    short* Qb   = (short*)d_ws;            // [N][128] bf16 (Q,K,V contiguous)
    short* Kb   = Qb + NC;
    short* Vb   = Kb + NC;
    short* Ob   = Vb + NC;                 // [N][128] bf16 (pre-normalized o)
    int*   EI   = (int*)(Ob + NC);         // int32 indices, 2*E
    short* WB   = (short*)(EI + 2 * E);    // 4 x 16384 bf16 weights
    float* mpart = (float*)(WB + 65536);   // [gbN][8]
    float* zpart = mpart + (size_t)gbN * 8;
    float* MZ    = zpart + (size_t)gbN * 8; // 16: M[8], Z[8]
    float* mloc  = MZ + 16;                 // [N*8]
    float* sc    = mloc + (size_t)N * 8;    // [N*8]
    int*   flag  = (int*)(sc + (size_t)N * 8);
    int* deg      = flag + 16;             // N
    int* rowstart = deg + N;               // N+1
    int* cursor   = rowstart + N + 1;      // N
    int* bsum     = cursor + N;            // 512
    int* ecol     = bsum + 512;            // E (binned cols)

    const int nbS = (N + TPB - 1) / TPB;
    const int ebE = (E + TPB - 1) / TPB;

    // --- CSR build (independent of GEMMs) ---
    hipMemsetAsync(deg, 0, (size_t)N * sizeof(int), stream);
    detect_i64_kernel<<<1, 64, 0, stream>>>((const int*)eraw, flag);
    conv_hist_kernel<<<(2 * E + TPB - 1) / TPB, TPB, 0, stream>>>(eraw, E, flag, EI, deg);
    scan1_kernel<<<nbS, TPB, 0, stream>>>(deg, N, rowstart, bsum);
    scan2_kernel<<<1, 512, 0, stream>>>(bsum, nbS);
    scan3_kernel<<<nbS, TPB, 0, stream>>>(rowstart, cursor, N, E, bsum);
    fill_kernel<<<ebE, TPB, 0, stream>>>(EI, E, cursor, ecol);

    // --- Projections (round-8 structure) ---
    wconv_kernel<<<256, TPB, 0, stream>>>(Wq, Wk, Wv, Wo, WB);
    const int gb = (N + 127) / 128;                 // X tiles (782)
    const int qkvgrid = 8 * 3 * ((gb + 7) / 8);     // XCD-co-located mapping
    gemm_qkv_kernel<<<qkvgrid, TPB, 0, stream>>>(feat, N, gb, WB, bq, bk, bv, Qb, NC);

    // --- Fused flash edge pass (scores + online softmax + V accumulate) ---
    flash_edge_kernel<<<gbN, TPB, 0, stream>>>(Qb, Kb, Vb, ecol, rowstart, N,
                                               Ob, mloc, mpart, zpart);
    stats_reduce_kernel<<<1, TPB, 0, stream>>>(mpart, zpart, gbN, MZ);
    scale_prep_kernel<<<gbN, TPB, 0, stream>>>(mloc, MZ, N * 8, sc);

    // --- Output projection with folded softmax scale (bf16 in, fp32 out) ---
    gemm_out_kernel<<<gb, TPB, 0, stream>>>(Ob, sc, N, WB + 3 * 16384, bo, (float*)d_out);
}

// Round 12
// 259.700 us; speedup vs baseline: 1.9990x; 1.1525x over previous
//
#include <hip/hip_runtime.h>

// HyperbolicAttention: N=100000 nodes, C=128, H=8 heads, D=16, E=640000 edges.
// Round 12: revert to the round-8 configuration (best measured, 259us):
//   - GEMMs: one-shot 128-row blocks, all loads up front, LDS frag-major W,
//     swapped-operand MFMA, XCD-co-located time-aligned QKV slices.
//   - Edge pipeline: CSR-first, two lightweight high-occupancy passes
//     (csr_score_stats, gather) with 2-deep prefetch.
// r9 (persistent), r10 (independent-wave), r11 (flash fusion) all regressed:
// GEMM needs time-aligned co-location + low fixed cost; edge passes need
// occupancy (latency-bound L3 fill), not fewer bytes.

#define TPB 256

typedef __attribute__((ext_vector_type(8))) short short8;
typedef __attribute__((ext_vector_type(4))) short short4v;
typedef __attribute__((ext_vector_type(4))) float f32x4;

// fp32 -> bf16 round-to-nearest-even
__device__ __forceinline__ short f2bf(float f) {
    unsigned u = __float_as_uint(f);
    u += 0x7fffu + ((u >> 16) & 1u);
    return (short)(u >> 16);
}
// bf16 -> fp32
__device__ __forceinline__ float bf2f(short s) {
    return __uint_as_float(((unsigned)(unsigned short)s) << 16);
}

// ---------------------------------------------------------------------------
// Convert the four 128x128 fp32 weight matrices to bf16 (row-major, packed).
// ---------------------------------------------------------------------------
__global__ void wconv_kernel(const float* __restrict__ W0, const float* __restrict__ W1,
                             const float* __restrict__ W2, const float* __restrict__ W3,
                             short* __restrict__ out)
{
    int i = blockIdx.x * TPB + threadIdx.x;   // 0..65535
    if (i >= 65536) return;
    const float* W = (i < 16384) ? W0 : (i < 32768) ? W1 : (i < 49152) ? W2 : W3;
    out[i] = f2bf(W[i & 16383]);
}

// ---------------------------------------------------------------------------
// Shared GEMM body: Y = X @ W^T + b for one 128-row tile (xblk).
// All global loads (8 W-frags + 16 X-float4 / 8 X-short8) issued before any
// wait -> deep MLP per wave. W LDS frag-major; swapped-operand MFMA; lane
// holds x-row=l15 and 4 consecutive output cols -> vectorized stores.
// ---------------------------------------------------------------------------
template<bool IN_BF16, bool OUT_BF16>
__device__ __forceinline__ void gemm_body(
    const void* __restrict__ Xv, int nrows,
    const short* __restrict__ Wb, const float* __restrict__ bias,
    void* __restrict__ Yv, int xblk)
{
    __shared__ short lw[16384];   // 32 KiB W, frag-major
    const int tid = threadIdx.x;

    // --- issue W global loads (8 x 16B per thread) ---
    short8 wreg[8];
    #pragma unroll
    for (int r = 0; r < 8; ++r) {
        int c = r * 256 + tid;              // chunk id 0..2047
        int fragid = c >> 6, ln = c & 63;
        int n = fragid >> 2, kc = fragid & 3;
        wreg[r] = *(const short8*)&Wb[(n*16 + (ln & 15))*128 + kc*32 + (ln >> 4)*8];
    }

    const int wid = tid >> 6;
    const int lane = tid & 63;
    const int l15 = lane & 15;
    const int lh  = lane >> 4;
    const int rowbase = xblk * 128 + wid * 32;
    const int r0 = rowbase + l15, r1 = r0 + 16;
    const bool vv0 = r0 < nrows, vv1 = r1 < nrows;

    // --- issue ALL X loads, then convert ---
    short8 xfr[4][2];   // [kc][row-group]
    if (IN_BF16) {
        const short* Xb = (const short*)Xv;
        #pragma unroll
        for (int kc = 0; kc < 4; ++kc) {
            xfr[kc][0] = vv0 ? *(const short8*)&Xb[(size_t)r0*128 + kc*32 + lh*8]
                             : (short8)(short)0;
            xfr[kc][1] = vv1 ? *(const short8*)&Xb[(size_t)r1*128 + kc*32 + lh*8]
                             : (short8)(short)0;
        }
    } else {
        const float* Xf = (const float*)Xv;
        const float4* P0 = (const float4*)(Xf + (size_t)r0 * 128);
        const float4* P1 = (const float4*)(Xf + (size_t)r1 * 128);
        float4 xa[4][2], xb[4][2];
        #pragma unroll
        for (int kc = 0; kc < 4; ++kc) {
            xa[kc][0] = vv0 ? P0[kc*8 + lh*2]     : make_float4(0.f,0.f,0.f,0.f);
            xb[kc][0] = vv0 ? P0[kc*8 + lh*2 + 1] : make_float4(0.f,0.f,0.f,0.f);
            xa[kc][1] = vv1 ? P1[kc*8 + lh*2]     : make_float4(0.f,0.f,0.f,0.f);
            xb[kc][1] = vv1 ? P1[kc*8 + lh*2 + 1] : make_float4(0.f,0.f,0.f,0.f);
        }
        #pragma unroll
        for (int kc = 0; kc < 4; ++kc)
            #pragma unroll
            for (int g = 0; g < 2; ++g) {
                xfr[kc][g][0] = f2bf(xa[kc][g].x);
                xfr[kc][g][1] = f2bf(xa[kc][g].y);
                xfr[kc][g][2] = f2bf(xa[kc][g].z);
                xfr[kc][g][3] = f2bf(xa[kc][g].w);
                xfr[kc][g][4] = f2bf(xb[kc][g].x);
                xfr[kc][g][5] = f2bf(xb[kc][g].y);
                xfr[kc][g][6] = f2bf(xb[kc][g].z);
                xfr[kc][g][7] = f2bf(xb[kc][g].w);
            }
    }

    // --- W regs -> LDS, barrier ---
    #pragma unroll
    for (int r = 0; r < 8; ++r)
        *(short8*)&lw[(r * 256 + tid) * 8] = wreg[r];
    __syncthreads();

    // --- pure LDS + MFMA loop ---
    f32x4 acc[8][2];
    #pragma unroll
    for (int n = 0; n < 8; ++n) { acc[n][0] = (f32x4)0.f; acc[n][1] = (f32x4)0.f; }

    #pragma unroll
    for (int kc = 0; kc < 4; ++kc) {
        short8 wf[8];
        #pragma unroll
        for (int n = 0; n < 8; ++n)
            wf[n] = *(const short8*)&lw[((n*4 + kc)*64 + lane) * 8];
        #pragma unroll
        for (int n = 0; n < 8; ++n) {
            acc[n][0] = __builtin_amdgcn_mfma_f32_16x16x32_bf16(wf[n], xfr[kc][0], acc[n][0], 0, 0, 0);
            acc[n][1] = __builtin_amdgcn_mfma_f32_16x16x32_bf16(wf[n], xfr[kc][1], acc[n][1], 0, 0, 0);
        }
    }

    // --- epilogue ---
    #pragma unroll
    for (int g = 0; g < 2; ++g) {
        int row = rowbase + g*16 + l15;
        if (row >= nrows) continue;
        #pragma unroll
        for (int n = 0; n < 8; ++n) {
            float4 b4 = *(const float4*)&bias[n*16 + lh*4];
            float y0 = acc[n][g][0] + b4.x;
            float y1 = acc[n][g][1] + b4.y;
            float y2 = acc[n][g][2] + b4.z;
            float y3 = acc[n][g][3] + b4.w;
            if (OUT_BF16) {
                short4v s; s[0]=f2bf(y0); s[1]=f2bf(y1); s[2]=f2bf(y2); s[3]=f2bf(y3);
                *(short4v*)&((short*)Yv)[(size_t)row * 128 + n*16 + lh*4] = s;
            } else {
                *(float4*)&((float*)Yv)[(size_t)row * 128 + n*16 + lh*4] =
                    make_float4(y0, y1, y2, y3);
            }
        }
    }
}

// Output projection: bf16 in, fp32 out.
__global__ __launch_bounds__(256) void gemm_out_kernel(
    const short* __restrict__ Xb, int nrows,
    const short* __restrict__ Wb, const float* __restrict__ bias,
    float* __restrict__ Y)
{
    gemm_body<true, false>(Xb, nrows, Wb, bias, Y, blockIdx.x);
}

// Fused QKV with XCD co-location: the 3 W-slices of X-tile x map to block ids
// b = (x&7) + 8*(3*(x>>3) + w)  ->  all share b%8 (assumed XCD) so the X rows
// are fetched from HBM once per XCD and L2-shared by the other two slices.
__global__ __launch_bounds__(256) void gemm_qkv_kernel(
    const float* __restrict__ X, int nrows, int nxblk,
    const short* __restrict__ WB,
    const float* __restrict__ bq, const float* __restrict__ bk,
    const float* __restrict__ bv,
    short* __restrict__ Yb, size_t slice)
{
    int b = blockIdx.x;
    int k = b & 7, j = b >> 3;
    int jd = j / 3, w = j - 3 * jd;
    int x = k + 8 * jd;
    if (x >= nxblk) return;
    const float* bias = (w == 0) ? bq : (w == 1) ? bk : bv;
    gemm_body<false, true>(X, nrows, WB + w * 16384, bias,
                           Yb + (size_t)w * slice, x);
}

// ---------------------------------------------------------------------------
// edge_index may arrive as int64 (reference) or int32. Detect on device.
// ---------------------------------------------------------------------------
__global__ void detect_i64_kernel(const int* __restrict__ raw, int* __restrict__ flag)
{
    if (blockIdx.x == 0 && threadIdx.x == 0) {
        int odd_nonzero = 0;
        for (int i = 0; i < 128; ++i)
            if (raw[2 * i + 1] != 0) odd_nonzero = 1;
        *flag = odd_nonzero ? 0 : 1;  // 1 => int64 layout
    }
}

// Convert to int32; simultaneously histogram destination rows (i < E).
__global__ void conv_hist_kernel(const void* __restrict__ raw, int E,
                                 const int* __restrict__ flag,
                                 int* __restrict__ out, int* __restrict__ deg)
{
    int i = blockIdx.x * TPB + threadIdx.x;
    if (i >= 2 * E) return;
    int v;
    if (*flag) v = (int)((const long long*)raw)[i];
    else       v = ((const int*)raw)[i];
    out[i] = v;
    if (i < E) atomicAdd(&deg[v], 1);
}

// ---------------------------------------------------------------------------
// CSR scan: block-local exclusive scan, block-sum scan, add-back (also
// initializes cursor = rowstart).
// ---------------------------------------------------------------------------
__global__ void scan1_kernel(const int* __restrict__ deg, int n,
                             int* __restrict__ rowstart, int* __restrict__ bsum)
{
    __shared__ int sm[TPB];
    int t = threadIdx.x;
    int gid = blockIdx.x * TPB + t;
    int v = (gid < n) ? deg[gid] : 0;
    sm[t] = v;
    __syncthreads();
    for (int off = 1; off < TPB; off <<= 1) {
        int x = (t >= off) ? sm[t - off] : 0;
        __syncthreads();
        sm[t] += x;
        __syncthreads();
    }
    if (gid < n) rowstart[gid] = sm[t] - v;
    if (t == TPB - 1) bsum[blockIdx.x] = sm[t];
}

__global__ void scan2_kernel(int* __restrict__ bsum, int nb)
{
    __shared__ int sm[512];
    int t = threadIdx.x;
    int v = (t < nb) ? bsum[t] : 0;
    sm[t] = v;
    __syncthreads();
    for (int off = 1; off < 512; off <<= 1) {
        int x = (t >= off) ? sm[t - off] : 0;
        __syncthreads();
        sm[t] += x;
        __syncthreads();
    }
    if (t < nb) bsum[t] = sm[t] - v;
}

__global__ void scan3_kernel(int* __restrict__ rowstart, int* __restrict__ cursor,
                             int n, int E, const int* __restrict__ bsum)
{
    int gid = blockIdx.x * TPB + threadIdx.x;
    if (gid < n) {
        int v = rowstart[gid] + bsum[blockIdx.x];
        rowstart[gid] = v;
        cursor[gid] = v;
    }
    if (gid == 0) rowstart[n] = E;
}

// Bin edges by destination: ecol[p] = col of edge, p in the dest's segment.
__global__ void fill_kernel(const int* __restrict__ ei, int E,
                            int* __restrict__ cursor, int* __restrict__ ecol)
{
    int e = blockIdx.x * TPB + threadIdx.x;
    if (e >= E) return;
    int pos = atomicAdd(&cursor[ei[e]], 1);
    ecol[pos] = ei[E + e];
}

// ---------------------------------------------------------------------------
// CSR-ordered scores + fused online softmax partials, 2-deep prefetch.
// thread = (node, h): Q slice in regs; K rows shared by the node's 8 lanes;
// S written sequentially at [p*8+h].
// ---------------------------------------------------------------------------
__global__ __launch_bounds__(256) void csr_score_stats_kernel(
    const short* __restrict__ Qb, const short* __restrict__ Kb,
    const int* __restrict__ ecol, const int* __restrict__ rowstart, int N,
    float* __restrict__ S, float* __restrict__ mpart, float* __restrict__ zpart)
{
    int t = threadIdx.x;
    int idx = blockIdx.x * TPB + t;
    float m = -3.0e38f, z = 0.f;
    if (idx < N * 8) {
        int node = idx >> 3, h = idx & 7;
        const short8* q8 = (const short8*)(Qb + (size_t)node * 128 + h * 16);
        short8 q0 = q8[0], q1 = q8[1];
        int p0 = rowstart[node], p1 = rowstart[node + 1];
        if (p0 < p1) {
            const short8* kc = (const short8*)(Kb + (size_t)ecol[p0] * 128 + h * 16);
            short8 k0 = kc[0], k1 = kc[1];
            for (int p = p0; p < p1; ++p) {
                short8 k0n = k0, k1n = k1;
                if (p + 1 < p1) {
                    const short8* kn = (const short8*)(Kb + (size_t)ecol[p+1] * 128 + h * 16);
                    k0n = kn[0]; k1n = kn[1];
                }
                float dot = 0.f;
                #pragma unroll
                for (int i = 0; i < 8; ++i) {
                    dot += bf2f(q0[i]) * bf2f(k0[i]);
                    dot += bf2f(q1[i]) * bf2f(k1[i]);
                }
                float s = dot * 0.25f;  // 1/sqrt(16)
                S[(size_t)p * 8 + h] = s;
                float M = fmaxf(m, s);
                z = z * __expf(m - M) + __expf(s - M);
                m = M;
                k0 = k0n; k1 = k1n;
            }
        }
    }
    __shared__ float sm[TPB], sz[TPB];
    sm[t] = m; sz[t] = z;
    __syncthreads();
    for (int off = 128; off >= 8; off >>= 1) {
        if (t < off) {
            float m2 = sm[t + off], z2 = sz[t + off];
            float M = fmaxf(sm[t], m2);
            sz[t] = sz[t] * __expf(sm[t] - M) + z2 * __expf(m2 - M);
            sm[t] = M;
        }
        __syncthreads();
    }
    if (t < 8) {
        mpart[blockIdx.x * 8 + t] = sm[t];
        zpart[blockIdx.x * 8 + t] = sz[t];
    }
}

// One block: combine nb per-block partials -> MZ[h] (max), MZ[8+h] (Z).
__global__ void stats_reduce_kernel(const float* __restrict__ mpart,
                                    const float* __restrict__ zpart,
                                    int nb, float* __restrict__ MZ)
{
    int t = threadIdx.x;
    int h = t & 7, chunk = t >> 3;   // 32 chunks
    float m = -3.0e38f, z = 0.f;
    for (int i = chunk; i < nb; i += 32) {
        float m2 = mpart[i * 8 + h], z2 = zpart[i * 8 + h];
        float M = fmaxf(m, m2);
        z = z * __expf(m - M) + z2 * __expf(m2 - M);
        m = M;
    }
    __shared__ float sm[TPB], sz[TPB];
    sm[t] = m; sz[t] = z;
    __syncthreads();
    for (int off = 128; off >= 8; off >>= 1) {
        if (t < off) {
            float m2 = sm[t + off], z2 = sz[t + off];
            float M = fmaxf(sm[t], m2);
            sz[t] = sz[t] * __expf(sm[t] - M) + z2 * __expf(m2 - M);
            sm[t] = M;
        }
        __syncthreads();
    }
    if (t < 8) { MZ[t] = sm[t]; MZ[8 + t] = sz[t]; }
}

// ---------------------------------------------------------------------------
// Gather segment-sum, fused exp/normalize, 2-deep prefetch.
// thread = (node, head); S sequential; V rows shared by the node's 8 lanes.
// ---------------------------------------------------------------------------
__global__ __launch_bounds__(256) void gather_kernel(
    const float* __restrict__ S, const short* __restrict__ Vb,
    const int* __restrict__ ecol,
    const int* __restrict__ rowstart,
    const float* __restrict__ MZ, int N,
    short* __restrict__ outb)
{
    int idx = blockIdx.x * TPB + threadIdx.x;
    if (idx >= N * 8) return;
    int node = idx >> 3, h = idx & 7;
    float M = MZ[h];
    float invZ = 1.0f / MZ[8 + h];
    int p0 = rowstart[node], p1 = rowstart[node + 1];

    float a[16];
    #pragma unroll
    for (int i = 0; i < 16; ++i) a[i] = 0.f;

    if (p0 < p1) {
        const short8* vc = (const short8*)(Vb + (size_t)ecol[p0] * 128 + h * 16);
        short8 v0 = vc[0], v1 = vc[1];
        float sc = S[(size_t)p0 * 8 + h];
        for (int p = p0; p < p1; ++p) {
            short8 v0n = v0, v1n = v1;
            float sn = sc;
            if (p + 1 < p1) {
                const short8* vn = (const short8*)(Vb + (size_t)ecol[p+1] * 128 + h * 16);
                v0n = vn[0]; v1n = vn[1];
                sn = S[(size_t)(p+1) * 8 + h];
            }
            float w = __expf(sc - M) * invZ;
            #pragma unroll
            for (int i = 0; i < 8; ++i) {
                a[i]     += w * bf2f(v0[i]);
                a[8 + i] += w * bf2f(v1[i]);
            }
            v0 = v0n; v1 = v1n; sc = sn;
        }
    }
    short8 o0, o1;
    #pragma unroll
    for (int i = 0; i < 8; ++i) { o0[i] = f2bf(a[i]); o1[i] = f2bf(a[8 + i]); }
    short8* ob = (short8*)(outb + (size_t)node * 128 + h * 16);
    ob[0] = o0; ob[1] = o1;
}

// ---------------------------------------------------------------------------
extern "C" void kernel_launch(void* const* d_in, const int* in_sizes, int n_in,
                              void* d_out, int out_size, void* d_ws, size_t ws_size,
                              hipStream_t stream)
{
    const float* feat = (const float*)d_in[0];
    const void*  eraw = d_in[1];
    const float* Wq = (const float*)d_in[2];
    const float* bq = (const float*)d_in[3];
    const float* Wk = (const float*)d_in[4];
    const float* bk = (const float*)d_in[5];
    const float* Wv = (const float*)d_in[6];
    const float* bv = (const float*)d_in[7];
    const float* Wo = (const float*)d_in[8];
    const float* bo = (const float*)d_in[9];

    const int N = in_sizes[0] / 128;
    const int E = in_sizes[1] / 2;
    const size_t NC = (size_t)N * 128;
    const int EH = E * 8;
    const int gbN = (N * 8 + TPB - 1) / TPB;   // node-head grid (scores/gather)

    // Workspace layout
    short* Qb   = (short*)d_ws;            // [N][128] bf16 (Q,K,V contiguous)
    short* Kb   = Qb + NC;
    short* Vb   = Kb + NC;
    short* ACCb = Vb + NC;                 // [N][128] bf16
    float* S    = (float*)(ACCb + NC);     // [E*8] scores, CSR order
    int*   EI   = (int*)(S + EH);          // int32 indices, 2*E
    short* WB   = (short*)(EI + 2 * E);    // 4 x 16384 bf16 weights
    float* mpart = (float*)(WB + 65536);   // [gbN][8]
    float* zpart = mpart + (size_t)gbN * 8;
    float* MZ    = zpart + (size_t)gbN * 8; // 16: M[8], Z[8]
    int*   flag  = (int*)(MZ + 16);
    int* deg      = flag + 16;             // N
    int* rowstart = deg + N;               // N+1
    int* cursor   = rowstart + N + 1;      // N
    int* bsum     = cursor + N;            // 512
    int* ecol     = bsum + 512;            // E (binned cols)

    const int nbS = (N + TPB - 1) / TPB;
    const int ebE = (E + TPB - 1) / TPB;

    // --- CSR build (independent of GEMMs) ---
    hipMemsetAsync(deg, 0, (size_t)N * sizeof(int), stream);
    detect_i64_kernel<<<1, 64, 0, stream>>>((const int*)eraw, flag);
    conv_hist_kernel<<<(2 * E + TPB - 1) / TPB, TPB, 0, stream>>>(eraw, E, flag, EI, deg);
    scan1_kernel<<<nbS, TPB, 0, stream>>>(deg, N, rowstart, bsum);
    scan2_kernel<<<1, 512, 0, stream>>>(bsum, nbS);
    scan3_kernel<<<nbS, TPB, 0, stream>>>(rowstart, cursor, N, E, bsum);
    fill_kernel<<<ebE, TPB, 0, stream>>>(EI, E, cursor, ecol);

    // --- Projections ---
    wconv_kernel<<<256, TPB, 0, stream>>>(Wq, Wk, Wv, Wo, WB);
    const int gb = (N + 127) / 128;                 // X tiles
    const int qkvgrid = 8 * 3 * ((gb + 7) / 8);     // XCD-co-located mapping
    gemm_qkv_kernel<<<qkvgrid, TPB, 0, stream>>>(feat, N, gb, WB, bq, bk, bv, Qb, NC);

    // --- Scores + softmax stats (CSR order) ---
    csr_score_stats_kernel<<<gbN, TPB, 0, stream>>>(Qb, Kb, ecol, rowstart, N,
                                                    S, mpart, zpart);
    stats_reduce_kernel<<<1, TPB, 0, stream>>>(mpart, zpart, gbN, MZ);

    // --- Gather segment-sum with fused exp/normalize -> bf16 ACC ---
    gather_kernel<<<gbN, TPB, 0, stream>>>(S, Vb, ecol, rowstart, MZ, N, ACCb);

    // --- Output projection (bf16 in, fp32 out) ---
    gemm_out_kernel<<<gb, TPB, 0, stream>>>(ACCb, N, WB + 3 * 16384, bo, (float*)d_out);
}

// Round 13
// 254.497 us; speedup vs baseline: 2.0399x; 1.0204x over previous
//
#include <hip/hip_runtime.h>

// HyperbolicAttention: N=100000 nodes, C=128, H=8 heads, D=16, E=640000 edges.
// Round 13: r8/r12 baseline + depth-2 software pipeline in the two edge
//           passes (latency-bound random L3 gathers, VGPR stays <64) and
//           dispatch merges (memset+detect -> init; wconv folded into
//           conv_hist grid tail).

#define TPB 256

typedef __attribute__((ext_vector_type(8))) short short8;
typedef __attribute__((ext_vector_type(4))) short short4v;
typedef __attribute__((ext_vector_type(4))) float f32x4;

// fp32 -> bf16 round-to-nearest-even
__device__ __forceinline__ short f2bf(float f) {
    unsigned u = __float_as_uint(f);
    u += 0x7fffu + ((u >> 16) & 1u);
    return (short)(u >> 16);
}
// bf16 -> fp32
__device__ __forceinline__ float bf2f(short s) {
    return __uint_as_float(((unsigned)(unsigned short)s) << 16);
}

// ---------------------------------------------------------------------------
// Shared GEMM body (round-8, validated 58us QKV): one 128-row tile per block;
// all global loads (8 W-frags + 16 X-float4 / 8 X-short8) issued before any
// wait; W LDS frag-major; swapped-operand MFMA; vectorized stores.
// ---------------------------------------------------------------------------
template<bool IN_BF16, bool OUT_BF16>
__device__ __forceinline__ void gemm_body(
    const void* __restrict__ Xv, int nrows,
    const short* __restrict__ Wb, const float* __restrict__ bias,
    void* __restrict__ Yv, int xblk)
{
    __shared__ short lw[16384];   // 32 KiB W, frag-major
    const int tid = threadIdx.x;

    short8 wreg[8];
    #pragma unroll
    for (int r = 0; r < 8; ++r) {
        int c = r * 256 + tid;              // chunk id 0..2047
        int fragid = c >> 6, ln = c & 63;
        int n = fragid >> 2, kc = fragid & 3;
        wreg[r] = *(const short8*)&Wb[(n*16 + (ln & 15))*128 + kc*32 + (ln >> 4)*8];
    }

    const int wid = tid >> 6;
    const int lane = tid & 63;
    const int l15 = lane & 15;
    const int lh  = lane >> 4;
    const int rowbase = xblk * 128 + wid * 32;
    const int r0 = rowbase + l15, r1 = r0 + 16;
    const bool vv0 = r0 < nrows, vv1 = r1 < nrows;

    short8 xfr[4][2];   // [kc][row-group]
    if (IN_BF16) {
        const short* Xb = (const short*)Xv;
        #pragma unroll
        for (int kc = 0; kc < 4; ++kc) {
            xfr[kc][0] = vv0 ? *(const short8*)&Xb[(size_t)r0*128 + kc*32 + lh*8]
                             : (short8)(short)0;
            xfr[kc][1] = vv1 ? *(const short8*)&Xb[(size_t)r1*128 + kc*32 + lh*8]
                             : (short8)(short)0;
        }
    } else {
        const float* Xf = (const float*)Xv;
        const float4* P0 = (const float4*)(Xf + (size_t)r0 * 128);
        const float4* P1 = (const float4*)(Xf + (size_t)r1 * 128);
        float4 xa[4][2], xb[4][2];
        #pragma unroll
        for (int kc = 0; kc < 4; ++kc) {
            xa[kc][0] = vv0 ? P0[kc*8 + lh*2]     : make_float4(0.f,0.f,0.f,0.f);
            xb[kc][0] = vv0 ? P0[kc*8 + lh*2 + 1] : make_float4(0.f,0.f,0.f,0.f);
            xa[kc][1] = vv1 ? P1[kc*8 + lh*2]     : make_float4(0.f,0.f,0.f,0.f);
            xb[kc][1] = vv1 ? P1[kc*8 + lh*2 + 1] : make_float4(0.f,0.f,0.f,0.f);
        }
        #pragma unroll
        for (int kc = 0; kc < 4; ++kc)
            #pragma unroll
            for (int g = 0; g < 2; ++g) {
                xfr[kc][g][0] = f2bf(xa[kc][g].x);
                xfr[kc][g][1] = f2bf(xa[kc][g].y);
                xfr[kc][g][2] = f2bf(xa[kc][g].z);
                xfr[kc][g][3] = f2bf(xa[kc][g].w);
                xfr[kc][g][4] = f2bf(xb[kc][g].x);
                xfr[kc][g][5] = f2bf(xb[kc][g].y);
                xfr[kc][g][6] = f2bf(xb[kc][g].z);
                xfr[kc][g][7] = f2bf(xb[kc][g].w);
            }
    }

    #pragma unroll
    for (int r = 0; r < 8; ++r)
        *(short8*)&lw[(r * 256 + tid) * 8] = wreg[r];
    __syncthreads();

    f32x4 acc[8][2];
    #pragma unroll
    for (int n = 0; n < 8; ++n) { acc[n][0] = (f32x4)0.f; acc[n][1] = (f32x4)0.f; }

    #pragma unroll
    for (int kc = 0; kc < 4; ++kc) {
        short8 wf[8];
        #pragma unroll
        for (int n = 0; n < 8; ++n)
            wf[n] = *(const short8*)&lw[((n*4 + kc)*64 + lane) * 8];
        #pragma unroll
        for (int n = 0; n < 8; ++n) {
            acc[n][0] = __builtin_amdgcn_mfma_f32_16x16x32_bf16(wf[n], xfr[kc][0], acc[n][0], 0, 0, 0);
            acc[n][1] = __builtin_amdgcn_mfma_f32_16x16x32_bf16(wf[n], xfr[kc][1], acc[n][1], 0, 0, 0);
        }
    }

    #pragma unroll
    for (int g = 0; g < 2; ++g) {
        int row = rowbase + g*16 + l15;
        if (row >= nrows) continue;
        #pragma unroll
        for (int n = 0; n < 8; ++n) {
            float4 b4 = *(const float4*)&bias[n*16 + lh*4];
            float y0 = acc[n][g][0] + b4.x;
            float y1 = acc[n][g][1] + b4.y;
            float y2 = acc[n][g][2] + b4.z;
            float y3 = acc[n][g][3] + b4.w;
            if (OUT_BF16) {
                short4v s; s[0]=f2bf(y0); s[1]=f2bf(y1); s[2]=f2bf(y2); s[3]=f2bf(y3);
                *(short4v*)&((short*)Yv)[(size_t)row * 128 + n*16 + lh*4] = s;
            } else {
                *(float4*)&((float*)Yv)[(size_t)row * 128 + n*16 + lh*4] =
                    make_float4(y0, y1, y2, y3);
            }
        }
    }
}

// Output projection: bf16 in, fp32 out.
__global__ __launch_bounds__(256) void gemm_out_kernel(
    const short* __restrict__ Xb, int nrows,
    const short* __restrict__ Wb, const float* __restrict__ bias,
    float* __restrict__ Y)
{
    gemm_body<true, false>(Xb, nrows, Wb, bias, Y, blockIdx.x);
}

// Fused QKV with XCD co-location: slices of X-tile x at b=(x&7)+8*(3*(x>>3)+w)
// share b%8 (same XCD) and are time-aligned -> X fetched once per XCD.
__global__ __launch_bounds__(256) void gemm_qkv_kernel(
    const float* __restrict__ X, int nrows, int nxblk,
    const short* __restrict__ WB,
    const float* __restrict__ bq, const float* __restrict__ bk,
    const float* __restrict__ bv,
    short* __restrict__ Yb, size_t slice)
{
    int b = blockIdx.x;
    int k = b & 7, j = b >> 3;
    int jd = j / 3, w = j - 3 * jd;
    int x = k + 8 * jd;
    if (x >= nxblk) return;
    const float* bias = (w == 0) ? bq : (w == 1) ? bk : bv;
    gemm_body<false, true>(X, nrows, WB + w * 16384, bias,
                           Yb + (size_t)w * slice, x);
}

// ---------------------------------------------------------------------------
// init: zero deg (grid-stride) + detect int64-vs-int32 edge_index (block 0).
// ---------------------------------------------------------------------------
__global__ void init_kernel(int* __restrict__ deg, int n,
                            const int* __restrict__ raw, int* __restrict__ flag)
{
    int i = blockIdx.x * TPB + threadIdx.x;
    if (i < n) deg[i] = 0;
    if (blockIdx.x == 0 && threadIdx.x == 0) {
        int odd_nonzero = 0;
        for (int k = 0; k < 128; ++k)
            if (raw[2 * k + 1] != 0) odd_nonzero = 1;
        *flag = odd_nonzero ? 0 : 1;  // 1 => int64 layout
    }
}

// ---------------------------------------------------------------------------
// conv_hist + wconv fused: blocks [0, ebC) convert edge_index to int32 and
// histogram destinations; blocks [ebC, ebC+256) convert the 4 weight
// matrices to bf16.
// ---------------------------------------------------------------------------
__global__ void conv_hist_wconv_kernel(
    const void* __restrict__ raw, int E, const int* __restrict__ flag,
    int* __restrict__ out, int* __restrict__ deg, int ebC,
    const float* __restrict__ W0, const float* __restrict__ W1,
    const float* __restrict__ W2, const float* __restrict__ W3,
    short* __restrict__ WB)
{
    int b = blockIdx.x;
    if (b < ebC) {
        int i = b * TPB + threadIdx.x;
        if (i >= 2 * E) return;
        int v;
        if (*flag) v = (int)((const long long*)raw)[i];
        else       v = ((const int*)raw)[i];
        out[i] = v;
        if (i < E) atomicAdd(&deg[v], 1);
    } else {
        int i = (b - ebC) * TPB + threadIdx.x;   // 0..65535
        if (i >= 65536) return;
        const float* W = (i < 16384) ? W0 : (i < 32768) ? W1 : (i < 49152) ? W2 : W3;
        WB[i] = f2bf(W[i & 16383]);
    }
}

// ---------------------------------------------------------------------------
// CSR scan chain (unchanged).
// ---------------------------------------------------------------------------
__global__ void scan1_kernel(const int* __restrict__ deg, int n,
                             int* __restrict__ rowstart, int* __restrict__ bsum)
{
    __shared__ int sm[TPB];
    int t = threadIdx.x;
    int gid = blockIdx.x * TPB + t;
    int v = (gid < n) ? deg[gid] : 0;
    sm[t] = v;
    __syncthreads();
    for (int off = 1; off < TPB; off <<= 1) {
        int x = (t >= off) ? sm[t - off] : 0;
        __syncthreads();
        sm[t] += x;
        __syncthreads();
    }
    if (gid < n) rowstart[gid] = sm[t] - v;
    if (t == TPB - 1) bsum[blockIdx.x] = sm[t];
}

__global__ void scan2_kernel(int* __restrict__ bsum, int nb)
{
    __shared__ int sm[512];
    int t = threadIdx.x;
    int v = (t < nb) ? bsum[t] : 0;
    sm[t] = v;
    __syncthreads();
    for (int off = 1; off < 512; off <<= 1) {
        int x = (t >= off) ? sm[t - off] : 0;
        __syncthreads();
        sm[t] += x;
        __syncthreads();
    }
    if (t < nb) bsum[t] = sm[t] - v;
}

__global__ void scan3_kernel(int* __restrict__ rowstart, int* __restrict__ cursor,
                             int n, int E, const int* __restrict__ bsum)
{
    int gid = blockIdx.x * TPB + threadIdx.x;
    if (gid < n) {
        int v = rowstart[gid] + bsum[blockIdx.x];
        rowstart[gid] = v;
        cursor[gid] = v;
    }
    if (gid == 0) rowstart[n] = E;
}

// Bin edges by destination: ecol[p] = col of edge, p in the dest's segment.
__global__ void fill_kernel(const int* __restrict__ ei, int E,
                            int* __restrict__ cursor, int* __restrict__ ecol)
{
    int e = blockIdx.x * TPB + threadIdx.x;
    if (e >= E) return;
    int pos = atomicAdd(&cursor[ei[e]], 1);
    ecol[pos] = ei[E + e];
}

// ---------------------------------------------------------------------------
// CSR-ordered scores + fused online softmax partials, DEPTH-2 prefetch
// (3 named pipeline stages, static register names per rule #20).
// thread = (node, h): Q slice in regs; K rows shared by the node's 8 lanes;
// S written sequentially at [p*8+h].
// ---------------------------------------------------------------------------
__global__ __launch_bounds__(256) void csr_score_stats_kernel(
    const short* __restrict__ Qb, const short* __restrict__ Kb,
    const int* __restrict__ ecol, const int* __restrict__ rowstart, int N,
    float* __restrict__ S, float* __restrict__ mpart, float* __restrict__ zpart)
{
    int t = threadIdx.x;
    int idx = blockIdx.x * TPB + t;
    float m = -3.0e38f, z = 0.f;
    if (idx < N * 8) {
        int node = idx >> 3, h = idx & 7;
        const short8* q8 = (const short8*)(Qb + (size_t)node * 128 + h * 16);
        short8 q0 = q8[0], q1 = q8[1];
        int p0 = rowstart[node], p1 = rowstart[node + 1];
        if (p0 < p1) {
            short8 ka0, ka1, kb0, kb1;
            {
                const short8* kp = (const short8*)(Kb + (size_t)ecol[p0] * 128 + h * 16);
                ka0 = kp[0]; ka1 = kp[1];
            }
            if (p0 + 1 < p1) {
                const short8* kp = (const short8*)(Kb + (size_t)ecol[p0+1] * 128 + h * 16);
                kb0 = kp[0]; kb1 = kp[1];
            } else { kb0 = ka0; kb1 = ka1; }

            for (int p = p0; p < p1; ++p) {
                short8 kc0 = kb0, kc1 = kb1;
                if (p + 2 < p1) {
                    const short8* kp = (const short8*)(Kb + (size_t)ecol[p+2] * 128 + h * 16);
                    kc0 = kp[0]; kc1 = kp[1];
                }
                float dot = 0.f;
                #pragma unroll
                for (int i = 0; i < 8; ++i) {
                    dot += bf2f(q0[i]) * bf2f(ka0[i]);
                    dot += bf2f(q1[i]) * bf2f(ka1[i]);
                }
                float s = dot * 0.25f;  // 1/sqrt(16)
                S[(size_t)p * 8 + h] = s;
                float M = fmaxf(m, s);
                z = z * __expf(m - M) + __expf(s - M);
                m = M;
                ka0 = kb0; ka1 = kb1; kb0 = kc0; kb1 = kc1;
            }
        }
    }
    __shared__ float sm[TPB], sz[TPB];
    sm[t] = m; sz[t] = z;
    __syncthreads();
    for (int off = 128; off >= 8; off >>= 1) {
        if (t < off) {
            float m2 = sm[t + off], z2 = sz[t + off];
            float M = fmaxf(sm[t], m2);
            sz[t] = sz[t] * __expf(sm[t] - M) + z2 * __expf(m2 - M);
            sm[t] = M;
        }
        __syncthreads();
    }
    if (t < 8) {
        mpart[blockIdx.x * 8 + t] = sm[t];
        zpart[blockIdx.x * 8 + t] = sz[t];
    }
}

// One block: combine nb per-block partials -> MZ[h] (max), MZ[8+h] (Z).
__global__ void stats_reduce_kernel(const float* __restrict__ mpart,
                                    const float* __restrict__ zpart,
                                    int nb, float* __restrict__ MZ)
{
    int t = threadIdx.x;
    int h = t & 7, chunk = t >> 3;   // 32 chunks
    float m = -3.0e38f, z = 0.f;
    for (int i = chunk; i < nb; i += 32) {
        float m2 = mpart[i * 8 + h], z2 = zpart[i * 8 + h];
        float M = fmaxf(m, m2);
        z = z * __expf(m - M) + z2 * __expf(m2 - M);
        m = M;
    }
    __shared__ float sm[TPB], sz[TPB];
    sm[t] = m; sz[t] = z;
    __syncthreads();
    for (int off = 128; off >= 8; off >>= 1) {
        if (t < off) {
            float m2 = sm[t + off], z2 = sz[t + off];
            float M = fmaxf(sm[t], m2);
            sz[t] = sz[t] * __expf(sm[t] - M) + z2 * __expf(m2 - M);
            sm[t] = M;
        }
        __syncthreads();
    }
    if (t < 8) { MZ[t] = sm[t]; MZ[8 + t] = sz[t]; }
}

// ---------------------------------------------------------------------------
// Gather segment-sum, fused exp/normalize, DEPTH-2 prefetch (3 stages).
// thread = (node, head); S sequential; V rows shared by the node's 8 lanes.
// ---------------------------------------------------------------------------
__global__ __launch_bounds__(256) void gather_kernel(
    const float* __restrict__ S, const short* __restrict__ Vb,
    const int* __restrict__ ecol,
    const int* __restrict__ rowstart,
    const float* __restrict__ MZ, int N,
    short* __restrict__ outb)
{
    int idx = blockIdx.x * TPB + threadIdx.x;
    if (idx >= N * 8) return;
    int node = idx >> 3, h = idx & 7;
    float M = MZ[h];
    float invZ = 1.0f / MZ[8 + h];
    int p0 = rowstart[node], p1 = rowstart[node + 1];

    float a[16];
    #pragma unroll
    for (int i = 0; i < 16; ++i) a[i] = 0.f;

    if (p0 < p1) {
        short8 va0, va1, vb0, vb1;
        float sa, sb;
        {
            const short8* vp = (const short8*)(Vb + (size_t)ecol[p0] * 128 + h * 16);
            va0 = vp[0]; va1 = vp[1];
            sa = S[(size_t)p0 * 8 + h];
        }
        if (p0 + 1 < p1) {
            const short8* vp = (const short8*)(Vb + (size_t)ecol[p0+1] * 128 + h * 16);
            vb0 = vp[0]; vb1 = vp[1];
            sb = S[(size_t)(p0+1) * 8 + h];
        } else { vb0 = va0; vb1 = va1; sb = sa; }

        for (int p = p0; p < p1; ++p) {
            short8 vc0 = vb0, vc1 = vb1;
            float sc = sb;
            if (p + 2 < p1) {
                const short8* vp = (const short8*)(Vb + (size_t)ecol[p+2] * 128 + h * 16);
                vc0 = vp[0]; vc1 = vp[1];
                sc = S[(size_t)(p+2) * 8 + h];
            }
            float w = __expf(sa - M) * invZ;
            #pragma unroll
            for (int i = 0; i < 8; ++i) {
                a[i]     += w * bf2f(va0[i]);
                a[8 + i] += w * bf2f(va1[i]);
            }
            va0 = vb0; va1 = vb1; vb0 = vc0; vb1 = vc1;
            sa = sb; sb = sc;
        }
    }
    short8 o0, o1;
    #pragma unroll
    for (int i = 0; i < 8; ++i) { o0[i] = f2bf(a[i]); o1[i] = f2bf(a[8 + i]); }
    short8* ob = (short8*)(outb + (size_t)node * 128 + h * 16);
    ob[0] = o0; ob[1] = o1;
}

// ---------------------------------------------------------------------------
extern "C" void kernel_launch(void* const* d_in, const int* in_sizes, int n_in,
                              void* d_out, int out_size, void* d_ws, size_t ws_size,
                              hipStream_t stream)
{
    const float* feat = (const float*)d_in[0];
    const void*  eraw = d_in[1];
    const float* Wq = (const float*)d_in[2];
    const float* bq = (const float*)d_in[3];
    const float* Wk = (const float*)d_in[4];
    const float* bk = (const float*)d_in[5];
    const float* Wv = (const float*)d_in[6];
    const float* bv = (const float*)d_in[7];
    const float* Wo = (const float*)d_in[8];
    const float* bo = (const float*)d_in[9];

    const int N = in_sizes[0] / 128;
    const int E = in_sizes[1] / 2;
    const size_t NC = (size_t)N * 128;
    const int EH = E * 8;
    const int gbN = (N * 8 + TPB - 1) / TPB;   // node-head grid (scores/gather)

    // Workspace layout
    short* Qb   = (short*)d_ws;            // [N][128] bf16 (Q,K,V contiguous)
    short* Kb   = Qb + NC;
    short* Vb   = Kb + NC;
    short* ACCb = Vb + NC;                 // [N][128] bf16
    float* S    = (float*)(ACCb + NC);     // [E*8] scores, CSR order
    int*   EI   = (int*)(S + EH);          // int32 indices, 2*E
    short* WB   = (short*)(EI + 2 * E);    // 4 x 16384 bf16 weights
    float* mpart = (float*)(WB + 65536);   // [gbN][8]
    float* zpart = mpart + (size_t)gbN * 8;
    float* MZ    = zpart + (size_t)gbN * 8; // 16: M[8], Z[8]
    int*   flag  = (int*)(MZ + 16);
    int* deg      = flag + 16;             // N
    int* rowstart = deg + N;               // N+1
    int* cursor   = rowstart + N + 1;      // N
    int* bsum     = cursor + N;            // 512
    int* ecol     = bsum + 512;            // E (binned cols)

    const int nbS = (N + TPB - 1) / TPB;
    const int ebE = (E + TPB - 1) / TPB;
    const int ebC = (2 * E + TPB - 1) / TPB;

    // --- CSR build (independent of GEMMs) ---
    init_kernel<<<nbS, TPB, 0, stream>>>(deg, N, (const int*)eraw, flag);
    conv_hist_wconv_kernel<<<ebC + 256, TPB, 0, stream>>>(
        eraw, E, flag, EI, deg, ebC, Wq, Wk, Wv, Wo, WB);
    scan1_kernel<<<nbS, TPB, 0, stream>>>(deg, N, rowstart, bsum);
    scan2_kernel<<<1, 512, 0, stream>>>(bsum, nbS);
    scan3_kernel<<<nbS, TPB, 0, stream>>>(rowstart, cursor, N, E, bsum);
    fill_kernel<<<ebE, TPB, 0, stream>>>(EI, E, cursor, ecol);

    // --- Projections ---
    const int gb = (N + 127) / 128;                 // X tiles
    const int qkvgrid = 8 * 3 * ((gb + 7) / 8);     // XCD-co-located mapping
    gemm_qkv_kernel<<<qkvgrid, TPB, 0, stream>>>(feat, N, gb, WB, bq, bk, bv, Qb, NC);

    // --- Scores + softmax stats (CSR order) ---
    csr_score_stats_kernel<<<gbN, TPB, 0, stream>>>(Qb, Kb, ecol, rowstart, N,
                                                    S, mpart, zpart);
    stats_reduce_kernel<<<1, TPB, 0, stream>>>(mpart, zpart, gbN, MZ);

    // --- Gather segment-sum with fused exp/normalize -> bf16 ACC ---
    gather_kernel<<<gbN, TPB, 0, stream>>>(S, Vb, ecol, rowstart, MZ, N, ACCb);

    // --- Output projection (bf16 in, fp32 out) ---
    gemm_out_kernel<<<gb, TPB, 0, stream>>>(ACCb, N, WB + 3 * 16384, bo, (float*)d_out);
}

// Round 14
// 250.865 us; speedup vs baseline: 2.0694x; 1.0145x over previous
//
#include <hip/hip_runtime.h>

// HyperbolicAttention: N=100000 nodes, C=128, H=8 heads, D=16, E=640000 edges.
// Round 14: r13 + EDGE-PARALLEL CSR-ordered scores (thread = (position, head),
//           perfect load balance; fill also emits erow[pos]). Gather keeps the
//           r13 node-parallel depth-2 form (needs per-node accumulation).

#define TPB 256

typedef __attribute__((ext_vector_type(8))) short short8;
typedef __attribute__((ext_vector_type(4))) short short4v;
typedef __attribute__((ext_vector_type(4))) float f32x4;

// fp32 -> bf16 round-to-nearest-even
__device__ __forceinline__ short f2bf(float f) {
    unsigned u = __float_as_uint(f);
    u += 0x7fffu + ((u >> 16) & 1u);
    return (short)(u >> 16);
}
// bf16 -> fp32
__device__ __forceinline__ float bf2f(short s) {
    return __uint_as_float(((unsigned)(unsigned short)s) << 16);
}

// ---------------------------------------------------------------------------
// Shared GEMM body (round-8, validated): one 128-row tile per block; all
// global loads issued before any wait; W LDS frag-major; swapped-operand MFMA.
// ---------------------------------------------------------------------------
template<bool IN_BF16, bool OUT_BF16>
__device__ __forceinline__ void gemm_body(
    const void* __restrict__ Xv, int nrows,
    const short* __restrict__ Wb, const float* __restrict__ bias,
    void* __restrict__ Yv, int xblk)
{
    __shared__ short lw[16384];   // 32 KiB W, frag-major
    const int tid = threadIdx.x;

    short8 wreg[8];
    #pragma unroll
    for (int r = 0; r < 8; ++r) {
        int c = r * 256 + tid;              // chunk id 0..2047
        int fragid = c >> 6, ln = c & 63;
        int n = fragid >> 2, kc = fragid & 3;
        wreg[r] = *(const short8*)&Wb[(n*16 + (ln & 15))*128 + kc*32 + (ln >> 4)*8];
    }

    const int wid = tid >> 6;
    const int lane = tid & 63;
    const int l15 = lane & 15;
    const int lh  = lane >> 4;
    const int rowbase = xblk * 128 + wid * 32;
    const int r0 = rowbase + l15, r1 = r0 + 16;
    const bool vv0 = r0 < nrows, vv1 = r1 < nrows;

    short8 xfr[4][2];   // [kc][row-group]
    if (IN_BF16) {
        const short* Xb = (const short*)Xv;
        #pragma unroll
        for (int kc = 0; kc < 4; ++kc) {
            xfr[kc][0] = vv0 ? *(const short8*)&Xb[(size_t)r0*128 + kc*32 + lh*8]
                             : (short8)(short)0;
            xfr[kc][1] = vv1 ? *(const short8*)&Xb[(size_t)r1*128 + kc*32 + lh*8]
                             : (short8)(short)0;
        }
    } else {
        const float* Xf = (const float*)Xv;
        const float4* P0 = (const float4*)(Xf + (size_t)r0 * 128);
        const float4* P1 = (const float4*)(Xf + (size_t)r1 * 128);
        float4 xa[4][2], xb[4][2];
        #pragma unroll
        for (int kc = 0; kc < 4; ++kc) {
            xa[kc][0] = vv0 ? P0[kc*8 + lh*2]     : make_float4(0.f,0.f,0.f,0.f);
            xb[kc][0] = vv0 ? P0[kc*8 + lh*2 + 1] : make_float4(0.f,0.f,0.f,0.f);
            xa[kc][1] = vv1 ? P1[kc*8 + lh*2]     : make_float4(0.f,0.f,0.f,0.f);
            xb[kc][1] = vv1 ? P1[kc*8 + lh*2 + 1] : make_float4(0.f,0.f,0.f,0.f);
        }
        #pragma unroll
        for (int kc = 0; kc < 4; ++kc)
            #pragma unroll
            for (int g = 0; g < 2; ++g) {
                xfr[kc][g][0] = f2bf(xa[kc][g].x);
                xfr[kc][g][1] = f2bf(xa[kc][g].y);
                xfr[kc][g][2] = f2bf(xa[kc][g].z);
                xfr[kc][g][3] = f2bf(xa[kc][g].w);
                xfr[kc][g][4] = f2bf(xb[kc][g].x);
                xfr[kc][g][5] = f2bf(xb[kc][g].y);
                xfr[kc][g][6] = f2bf(xb[kc][g].z);
                xfr[kc][g][7] = f2bf(xb[kc][g].w);
            }
    }

    #pragma unroll
    for (int r = 0; r < 8; ++r)
        *(short8*)&lw[(r * 256 + tid) * 8] = wreg[r];
    __syncthreads();

    f32x4 acc[8][2];
    #pragma unroll
    for (int n = 0; n < 8; ++n) { acc[n][0] = (f32x4)0.f; acc[n][1] = (f32x4)0.f; }

    #pragma unroll
    for (int kc = 0; kc < 4; ++kc) {
        short8 wf[8];
        #pragma unroll
        for (int n = 0; n < 8; ++n)
            wf[n] = *(const short8*)&lw[((n*4 + kc)*64 + lane) * 8];
        #pragma unroll
        for (int n = 0; n < 8; ++n) {
            acc[n][0] = __builtin_amdgcn_mfma_f32_16x16x32_bf16(wf[n], xfr[kc][0], acc[n][0], 0, 0, 0);
            acc[n][1] = __builtin_amdgcn_mfma_f32_16x16x32_bf16(wf[n], xfr[kc][1], acc[n][1], 0, 0, 0);
        }
    }

    #pragma unroll
    for (int g = 0; g < 2; ++g) {
        int row = rowbase + g*16 + l15;
        if (row >= nrows) continue;
        #pragma unroll
        for (int n = 0; n < 8; ++n) {
            float4 b4 = *(const float4*)&bias[n*16 + lh*4];
            float y0 = acc[n][g][0] + b4.x;
            float y1 = acc[n][g][1] + b4.y;
            float y2 = acc[n][g][2] + b4.z;
            float y3 = acc[n][g][3] + b4.w;
            if (OUT_BF16) {
                short4v s; s[0]=f2bf(y0); s[1]=f2bf(y1); s[2]=f2bf(y2); s[3]=f2bf(y3);
                *(short4v*)&((short*)Yv)[(size_t)row * 128 + n*16 + lh*4] = s;
            } else {
                *(float4*)&((float*)Yv)[(size_t)row * 128 + n*16 + lh*4] =
                    make_float4(y0, y1, y2, y3);
            }
        }
    }
}

// Output projection: bf16 in, fp32 out.
__global__ __launch_bounds__(256) void gemm_out_kernel(
    const short* __restrict__ Xb, int nrows,
    const short* __restrict__ Wb, const float* __restrict__ bias,
    float* __restrict__ Y)
{
    gemm_body<true, false>(Xb, nrows, Wb, bias, Y, blockIdx.x);
}

// Fused QKV with XCD co-location: slices of X-tile x at b=(x&7)+8*(3*(x>>3)+w)
// share b%8 (same XCD) and are time-aligned -> X fetched once per XCD.
__global__ __launch_bounds__(256) void gemm_qkv_kernel(
    const float* __restrict__ X, int nrows, int nxblk,
    const short* __restrict__ WB,
    const float* __restrict__ bq, const float* __restrict__ bk,
    const float* __restrict__ bv,
    short* __restrict__ Yb, size_t slice)
{
    int b = blockIdx.x;
    int k = b & 7, j = b >> 3;
    int jd = j / 3, w = j - 3 * jd;
    int x = k + 8 * jd;
    if (x >= nxblk) return;
    const float* bias = (w == 0) ? bq : (w == 1) ? bk : bv;
    gemm_body<false, true>(X, nrows, WB + w * 16384, bias,
                           Yb + (size_t)w * slice, x);
}

// ---------------------------------------------------------------------------
// init: zero deg (grid-stride) + detect int64-vs-int32 edge_index (block 0).
// ---------------------------------------------------------------------------
__global__ void init_kernel(int* __restrict__ deg, int n,
                            const int* __restrict__ raw, int* __restrict__ flag)
{
    int i = blockIdx.x * TPB + threadIdx.x;
    if (i < n) deg[i] = 0;
    if (blockIdx.x == 0 && threadIdx.x == 0) {
        int odd_nonzero = 0;
        for (int k = 0; k < 128; ++k)
            if (raw[2 * k + 1] != 0) odd_nonzero = 1;
        *flag = odd_nonzero ? 0 : 1;  // 1 => int64 layout
    }
}

// ---------------------------------------------------------------------------
// conv_hist + wconv fused: blocks [0, ebC) convert edge_index + histogram;
// blocks [ebC, ebC+256) convert the 4 weight matrices to bf16.
// ---------------------------------------------------------------------------
__global__ void conv_hist_wconv_kernel(
    const void* __restrict__ raw, int E, const int* __restrict__ flag,
    int* __restrict__ out, int* __restrict__ deg, int ebC,
    const float* __restrict__ W0, const float* __restrict__ W1,
    const float* __restrict__ W2, const float* __restrict__ W3,
    short* __restrict__ WB)
{
    int b = blockIdx.x;
    if (b < ebC) {
        int i = b * TPB + threadIdx.x;
        if (i >= 2 * E) return;
        int v;
        if (*flag) v = (int)((const long long*)raw)[i];
        else       v = ((const int*)raw)[i];
        out[i] = v;
        if (i < E) atomicAdd(&deg[v], 1);
    } else {
        int i = (b - ebC) * TPB + threadIdx.x;   // 0..65535
        if (i >= 65536) return;
        const float* W = (i < 16384) ? W0 : (i < 32768) ? W1 : (i < 49152) ? W2 : W3;
        WB[i] = f2bf(W[i & 16383]);
    }
}

// ---------------------------------------------------------------------------
// CSR scan chain.
// ---------------------------------------------------------------------------
__global__ void scan1_kernel(const int* __restrict__ deg, int n,
                             int* __restrict__ rowstart, int* __restrict__ bsum)
{
    __shared__ int sm[TPB];
    int t = threadIdx.x;
    int gid = blockIdx.x * TPB + t;
    int v = (gid < n) ? deg[gid] : 0;
    sm[t] = v;
    __syncthreads();
    for (int off = 1; off < TPB; off <<= 1) {
        int x = (t >= off) ? sm[t - off] : 0;
        __syncthreads();
        sm[t] += x;
        __syncthreads();
    }
    if (gid < n) rowstart[gid] = sm[t] - v;
    if (t == TPB - 1) bsum[blockIdx.x] = sm[t];
}

__global__ void scan2_kernel(int* __restrict__ bsum, int nb)
{
    __shared__ int sm[512];
    int t = threadIdx.x;
    int v = (t < nb) ? bsum[t] : 0;
    sm[t] = v;
    __syncthreads();
    for (int off = 1; off < 512; off <<= 1) {
        int x = (t >= off) ? sm[t - off] : 0;
        __syncthreads();
        sm[t] += x;
        __syncthreads();
    }
    if (t < nb) bsum[t] = sm[t] - v;
}

__global__ void scan3_kernel(int* __restrict__ rowstart, int* __restrict__ cursor,
                             int n, int E, const int* __restrict__ bsum)
{
    int gid = blockIdx.x * TPB + threadIdx.x;
    if (gid < n) {
        int v = rowstart[gid] + bsum[blockIdx.x];
        rowstart[gid] = v;
        cursor[gid] = v;
    }
    if (gid == 0) rowstart[n] = E;
}

// Bin edges by destination: ecol[p] = source col, erow[p] = dest row.
__global__ void fill_kernel(const int* __restrict__ ei, int E,
                            int* __restrict__ cursor,
                            int* __restrict__ ecol, int* __restrict__ erow)
{
    int e = blockIdx.x * TPB + threadIdx.x;
    if (e >= E) return;
    int r = ei[e];
    int pos = atomicAdd(&cursor[r], 1);
    ecol[pos] = ei[E + e];
    erow[pos] = r;
}

// ---------------------------------------------------------------------------
// EDGE-PARALLEL scores + fused online softmax partials.
// thread = (CSR position p, head h=idx&7), grid-stride (stride multiple of 8
// keeps the head class fixed per thread). Perfect load balance; S sequential;
// consecutive p share Q rows (CSR-sorted) -> L1 hits.
// ---------------------------------------------------------------------------
__global__ __launch_bounds__(256) void epar_score_stats_kernel(
    const short* __restrict__ Qb, const short* __restrict__ Kb,
    const int* __restrict__ erow, const int* __restrict__ ecol, int EH,
    float* __restrict__ S, float* __restrict__ mpart, float* __restrict__ zpart)
{
    int t = threadIdx.x;
    int stride = gridDim.x * TPB;
    float m = -3.0e38f, z = 0.f;
    for (int idx = blockIdx.x * TPB + t; idx < EH; idx += stride) {
        int p = idx >> 3, h = idx & 7;
        int r = erow[p], c = ecol[p];
        const short8* q8 = (const short8*)(Qb + (size_t)r * 128 + h * 16);
        const short8* k8 = (const short8*)(Kb + (size_t)c * 128 + h * 16);
        short8 q0 = q8[0], q1 = q8[1], k0 = k8[0], k1 = k8[1];
        float dot = 0.f;
        #pragma unroll
        for (int i = 0; i < 8; ++i) {
            dot += bf2f(q0[i]) * bf2f(k0[i]);
            dot += bf2f(q1[i]) * bf2f(k1[i]);
        }
        float s = dot * 0.25f;   // 1/sqrt(16)
        S[idx] = s;
        float M = fmaxf(m, s);
        z = z * __expf(m - M) + __expf(s - M);
        m = M;
    }
    __shared__ float sm[TPB], sz[TPB];
    sm[t] = m; sz[t] = z;
    __syncthreads();
    for (int off = 128; off >= 8; off >>= 1) {
        if (t < off) {
            float m2 = sm[t + off], z2 = sz[t + off];
            float M = fmaxf(sm[t], m2);
            sz[t] = sz[t] * __expf(sm[t] - M) + z2 * __expf(m2 - M);
            sm[t] = M;
        }
        __syncthreads();
    }
    if (t < 8) {
        mpart[blockIdx.x * 8 + t] = sm[t];
        zpart[blockIdx.x * 8 + t] = sz[t];
    }
}

// One block: combine nb per-block partials -> MZ[h] (max), MZ[8+h] (Z).
__global__ void stats_reduce_kernel(const float* __restrict__ mpart,
                                    const float* __restrict__ zpart,
                                    int nb, float* __restrict__ MZ)
{
    int t = threadIdx.x;
    int h = t & 7, chunk = t >> 3;   // 32 chunks
    float m = -3.0e38f, z = 0.f;
    for (int i = chunk; i < nb; i += 32) {
        float m2 = mpart[i * 8 + h], z2 = zpart[i * 8 + h];
        float M = fmaxf(m, m2);
        z = z * __expf(m - M) + z2 * __expf(m2 - M);
        m = M;
    }
    __shared__ float sm[TPB], sz[TPB];
    sm[t] = m; sz[t] = z;
    __syncthreads();
    for (int off = 128; off >= 8; off >>= 1) {
        if (t < off) {
            float m2 = sm[t + off], z2 = sz[t + off];
            float M = fmaxf(sm[t], m2);
            sz[t] = sz[t] * __expf(sm[t] - M) + z2 * __expf(m2 - M);
            sm[t] = M;
        }
        __syncthreads();
    }
    if (t < 8) { MZ[t] = sm[t]; MZ[8 + t] = sz[t]; }
}

// ---------------------------------------------------------------------------
// Gather segment-sum, fused exp/normalize, depth-2 prefetch (r13, validated).
// thread = (node, head); S sequential; V rows shared by the node's 8 lanes.
// ---------------------------------------------------------------------------
__global__ __launch_bounds__(256) void gather_kernel(
    const float* __restrict__ S, const short* __restrict__ Vb,
    const int* __restrict__ ecol,
    const int* __restrict__ rowstart,
    const float* __restrict__ MZ, int N,
    short* __restrict__ outb)
{
    int idx = blockIdx.x * TPB + threadIdx.x;
    if (idx >= N * 8) return;
    int node = idx >> 3, h = idx & 7;
    float M = MZ[h];
    float invZ = 1.0f / MZ[8 + h];
    int p0 = rowstart[node], p1 = rowstart[node + 1];

    float a[16];
    #pragma unroll
    for (int i = 0; i < 16; ++i) a[i] = 0.f;

    if (p0 < p1) {
        short8 va0, va1, vb0, vb1;
        float sa, sb;
        {
            const short8* vp = (const short8*)(Vb + (size_t)ecol[p0] * 128 + h * 16);
            va0 = vp[0]; va1 = vp[1];
            sa = S[(size_t)p0 * 8 + h];
        }
        if (p0 + 1 < p1) {
            const short8* vp = (const short8*)(Vb + (size_t)ecol[p0+1] * 128 + h * 16);
            vb0 = vp[0]; vb1 = vp[1];
            sb = S[(size_t)(p0+1) * 8 + h];
        } else { vb0 = va0; vb1 = va1; sb = sa; }

        for (int p = p0; p < p1; ++p) {
            short8 vc0 = vb0, vc1 = vb1;
            float sc = sb;
            if (p + 2 < p1) {
                const short8* vp = (const short8*)(Vb + (size_t)ecol[p+2] * 128 + h * 16);
                vc0 = vp[0]; vc1 = vp[1];
                sc = S[(size_t)(p+2) * 8 + h];
            }
            float w = __expf(sa - M) * invZ;
            #pragma unroll
            for (int i = 0; i < 8; ++i) {
                a[i]     += w * bf2f(va0[i]);
                a[8 + i] += w * bf2f(va1[i]);
            }
            va0 = vb0; va1 = vb1; vb0 = vc0; vb1 = vc1;
            sa = sb; sb = sc;
        }
    }
    short8 o0, o1;
    #pragma unroll
    for (int i = 0; i < 8; ++i) { o0[i] = f2bf(a[i]); o1[i] = f2bf(a[8 + i]); }
    short8* ob = (short8*)(outb + (size_t)node * 128 + h * 16);
    ob[0] = o0; ob[1] = o1;
}

// ---------------------------------------------------------------------------
extern "C" void kernel_launch(void* const* d_in, const int* in_sizes, int n_in,
                              void* d_out, int out_size, void* d_ws, size_t ws_size,
                              hipStream_t stream)
{
    const float* feat = (const float*)d_in[0];
    const void*  eraw = d_in[1];
    const float* Wq = (const float*)d_in[2];
    const float* bq = (const float*)d_in[3];
    const float* Wk = (const float*)d_in[4];
    const float* bk = (const float*)d_in[5];
    const float* Wv = (const float*)d_in[6];
    const float* bv = (const float*)d_in[7];
    const float* Wo = (const float*)d_in[8];
    const float* bo = (const float*)d_in[9];

    const int N = in_sizes[0] / 128;
    const int E = in_sizes[1] / 2;
    const size_t NC = (size_t)N * 128;
    const int EH = E * 8;
    const int gbN = (N * 8 + TPB - 1) / TPB;   // node-head grid (gather)
    const int EG  = 2500;                      // edge-stats grid (grid-stride)

    // Workspace layout
    short* Qb   = (short*)d_ws;            // [N][128] bf16 (Q,K,V contiguous)
    short* Kb   = Qb + NC;
    short* Vb   = Kb + NC;
    short* ACCb = Vb + NC;                 // [N][128] bf16
    float* S    = (float*)(ACCb + NC);     // [E*8] scores, CSR order
    int*   EI   = (int*)(S + EH);          // int32 indices, 2*E
    short* WB   = (short*)(EI + 2 * E);    // 4 x 16384 bf16 weights
    float* mpart = (float*)(WB + 65536);   // [EG][8]
    float* zpart = mpart + (size_t)EG * 8;
    float* MZ    = zpart + (size_t)EG * 8; // 16: M[8], Z[8]
    int*   flag  = (int*)(MZ + 16);
    int* deg      = flag + 16;             // N
    int* rowstart = deg + N;               // N+1
    int* cursor   = rowstart + N + 1;      // N
    int* bsum     = cursor + N;            // 512
    int* ecol     = bsum + 512;            // E (binned source cols)
    int* erow     = ecol + E;              // E (binned dest rows)

    const int nbS = (N + TPB - 1) / TPB;
    const int ebE = (E + TPB - 1) / TPB;
    const int ebC = (2 * E + TPB - 1) / TPB;

    // --- CSR build (independent of GEMMs) ---
    init_kernel<<<nbS, TPB, 0, stream>>>(deg, N, (const int*)eraw, flag);
    conv_hist_wconv_kernel<<<ebC + 256, TPB, 0, stream>>>(
        eraw, E, flag, EI, deg, ebC, Wq, Wk, Wv, Wo, WB);
    scan1_kernel<<<nbS, TPB, 0, stream>>>(deg, N, rowstart, bsum);
    scan2_kernel<<<1, 512, 0, stream>>>(bsum, nbS);
    scan3_kernel<<<nbS, TPB, 0, stream>>>(rowstart, cursor, N, E, bsum);
    fill_kernel<<<ebE, TPB, 0, stream>>>(EI, E, cursor, ecol, erow);

    // --- Projections ---
    const int gb = (N + 127) / 128;                 // X tiles
    const int qkvgrid = 8 * 3 * ((gb + 7) / 8);     // XCD-co-located mapping
    gemm_qkv_kernel<<<qkvgrid, TPB, 0, stream>>>(feat, N, gb, WB, bq, bk, bv, Qb, NC);

    // --- Scores + softmax stats (edge-parallel, CSR order) ---
    epar_score_stats_kernel<<<EG, TPB, 0, stream>>>(Qb, Kb, erow, ecol, EH,
                                                    S, mpart, zpart);
    stats_reduce_kernel<<<1, TPB, 0, stream>>>(mpart, zpart, EG, MZ);

    // --- Gather segment-sum with fused exp/normalize -> bf16 ACC ---
    gather_kernel<<<gbN, TPB, 0, stream>>>(S, Vb, ecol, rowstart, MZ, N, ACCb);

    // --- Output projection (bf16 in, fp32 out) ---
    gemm_out_kernel<<<gb, TPB, 0, stream>>>(ACCb, N, WB + 3 * 16384, bo, (float*)d_out);
}

// Round 15
// 248.853 us; speedup vs baseline: 2.0862x; 1.0081x over previous
//
#include <hip/hip_runtime.h>

// HyperbolicAttention: N=100000 nodes, C=128, H=8 heads, D=16, E=640000 edges.
// Round 15: r14 + W staged via __builtin_amdgcn_global_load_lds (16B async
//           global->LDS, no register round-trip): -32 VGPR, -8 ds_writes per
//           thread in both GEMMs. LDS layout already matches the HW pattern
//           (per-lane global src, wave-uniform-base+lane*16 LDS dest).

#define TPB 256

typedef __attribute__((ext_vector_type(8))) short short8;
typedef __attribute__((ext_vector_type(4))) short short4v;
typedef __attribute__((ext_vector_type(4))) float f32x4;

// fp32 -> bf16 round-to-nearest-even
__device__ __forceinline__ short f2bf(float f) {
    unsigned u = __float_as_uint(f);
    u += 0x7fffu + ((u >> 16) & 1u);
    return (short)(u >> 16);
}
// bf16 -> fp32
__device__ __forceinline__ float bf2f(short s) {
    return __uint_as_float(((unsigned)(unsigned short)s) << 16);
}

// ---------------------------------------------------------------------------
// Shared GEMM body: one 128-row tile per block; W staged to LDS via async
// global_load_lds (frag-major); all X loads issued before any wait;
// swapped-operand MFMA; vectorized stores.
// ---------------------------------------------------------------------------
template<bool IN_BF16, bool OUT_BF16>
__device__ __forceinline__ void gemm_body(
    const void* __restrict__ Xv, int nrows,
    const short* __restrict__ Wb, const float* __restrict__ bias,
    void* __restrict__ Yv, int xblk)
{
    __shared__ short lw[16384];   // 32 KiB W, frag-major
    const int tid = threadIdx.x;

    // --- stage W: async global->LDS, 8 x 16B per thread, no reg round-trip ---
    #pragma unroll
    for (int r = 0; r < 8; ++r) {
        int c = r * 256 + tid;              // chunk id 0..2047
        int fragid = c >> 6, ln = c & 63;
        int n = fragid >> 2, kc = fragid & 3;
        const short* gsrc = &Wb[(n*16 + (ln & 15))*128 + kc*32 + (ln >> 4)*8];
        __builtin_amdgcn_global_load_lds(
            (const __attribute__((address_space(1))) void*)gsrc,
            (__attribute__((address_space(3))) void*)&lw[c * 8],
            16, 0, 0);
    }

    const int wid = tid >> 6;
    const int lane = tid & 63;
    const int l15 = lane & 15;
    const int lh  = lane >> 4;
    const int rowbase = xblk * 128 + wid * 32;
    const int r0 = rowbase + l15, r1 = r0 + 16;
    const bool vv0 = r0 < nrows, vv1 = r1 < nrows;

    // --- issue ALL X loads, then convert ---
    short8 xfr[4][2];   // [kc][row-group]
    if (IN_BF16) {
        const short* Xb = (const short*)Xv;
        #pragma unroll
        for (int kc = 0; kc < 4; ++kc) {
            xfr[kc][0] = vv0 ? *(const short8*)&Xb[(size_t)r0*128 + kc*32 + lh*8]
                             : (short8)(short)0;
            xfr[kc][1] = vv1 ? *(const short8*)&Xb[(size_t)r1*128 + kc*32 + lh*8]
                             : (short8)(short)0;
        }
    } else {
        const float* Xf = (const float*)Xv;
        const float4* P0 = (const float4*)(Xf + (size_t)r0 * 128);
        const float4* P1 = (const float4*)(Xf + (size_t)r1 * 128);
        float4 xa[4][2], xb[4][2];
        #pragma unroll
        for (int kc = 0; kc < 4; ++kc) {
            xa[kc][0] = vv0 ? P0[kc*8 + lh*2]     : make_float4(0.f,0.f,0.f,0.f);
            xb[kc][0] = vv0 ? P0[kc*8 + lh*2 + 1] : make_float4(0.f,0.f,0.f,0.f);
            xa[kc][1] = vv1 ? P1[kc*8 + lh*2]     : make_float4(0.f,0.f,0.f,0.f);
            xb[kc][1] = vv1 ? P1[kc*8 + lh*2 + 1] : make_float4(0.f,0.f,0.f,0.f);
        }
        #pragma unroll
        for (int kc = 0; kc < 4; ++kc)
            #pragma unroll
            for (int g = 0; g < 2; ++g) {
                xfr[kc][g][0] = f2bf(xa[kc][g].x);
                xfr[kc][g][1] = f2bf(xa[kc][g].y);
                xfr[kc][g][2] = f2bf(xa[kc][g].z);
                xfr[kc][g][3] = f2bf(xa[kc][g].w);
                xfr[kc][g][4] = f2bf(xb[kc][g].x);
                xfr[kc][g][5] = f2bf(xb[kc][g].y);
                xfr[kc][g][6] = f2bf(xb[kc][g].z);
                xfr[kc][g][7] = f2bf(xb[kc][g].w);
            }
    }

    __syncthreads();   // drains vmcnt (global_load_lds) + barrier

    f32x4 acc[8][2];
    #pragma unroll
    for (int n = 0; n < 8; ++n) { acc[n][0] = (f32x4)0.f; acc[n][1] = (f32x4)0.f; }

    #pragma unroll
    for (int kc = 0; kc < 4; ++kc) {
        short8 wf[8];
        #pragma unroll
        for (int n = 0; n < 8; ++n)
            wf[n] = *(const short8*)&lw[((n*4 + kc)*64 + lane) * 8];
        #pragma unroll
        for (int n = 0; n < 8; ++n) {
            acc[n][0] = __builtin_amdgcn_mfma_f32_16x16x32_bf16(wf[n], xfr[kc][0], acc[n][0], 0, 0, 0);
            acc[n][1] = __builtin_amdgcn_mfma_f32_16x16x32_bf16(wf[n], xfr[kc][1], acc[n][1], 0, 0, 0);
        }
    }

    #pragma unroll
    for (int g = 0; g < 2; ++g) {
        int row = rowbase + g*16 + l15;
        if (row >= nrows) continue;
        #pragma unroll
        for (int n = 0; n < 8; ++n) {
            float4 b4 = *(const float4*)&bias[n*16 + lh*4];
            float y0 = acc[n][g][0] + b4.x;
            float y1 = acc[n][g][1] + b4.y;
            float y2 = acc[n][g][2] + b4.z;
            float y3 = acc[n][g][3] + b4.w;
            if (OUT_BF16) {
                short4v s; s[0]=f2bf(y0); s[1]=f2bf(y1); s[2]=f2bf(y2); s[3]=f2bf(y3);
                *(short4v*)&((short*)Yv)[(size_t)row * 128 + n*16 + lh*4] = s;
            } else {
                *(float4*)&((float*)Yv)[(size_t)row * 128 + n*16 + lh*4] =
                    make_float4(y0, y1, y2, y3);
            }
        }
    }
}

// Output projection: bf16 in, fp32 out.
__global__ __launch_bounds__(256) void gemm_out_kernel(
    const short* __restrict__ Xb, int nrows,
    const short* __restrict__ Wb, const float* __restrict__ bias,
    float* __restrict__ Y)
{
    gemm_body<true, false>(Xb, nrows, Wb, bias, Y, blockIdx.x);
}

// Fused QKV with XCD co-location: slices of X-tile x at b=(x&7)+8*(3*(x>>3)+w)
// share b%8 (same XCD) and are time-aligned -> X fetched once per XCD.
__global__ __launch_bounds__(256) void gemm_qkv_kernel(
    const float* __restrict__ X, int nrows, int nxblk,
    const short* __restrict__ WB,
    const float* __restrict__ bq, const float* __restrict__ bk,
    const float* __restrict__ bv,
    short* __restrict__ Yb, size_t slice)
{
    int b = blockIdx.x;
    int k = b & 7, j = b >> 3;
    int jd = j / 3, w = j - 3 * jd;
    int x = k + 8 * jd;
    if (x >= nxblk) return;
    const float* bias = (w == 0) ? bq : (w == 1) ? bk : bv;
    gemm_body<false, true>(X, nrows, WB + w * 16384, bias,
                           Yb + (size_t)w * slice, x);
}

// ---------------------------------------------------------------------------
// init: zero deg (grid-stride) + detect int64-vs-int32 edge_index (block 0).
// ---------------------------------------------------------------------------
__global__ void init_kernel(int* __restrict__ deg, int n,
                            const int* __restrict__ raw, int* __restrict__ flag)
{
    int i = blockIdx.x * TPB + threadIdx.x;
    if (i < n) deg[i] = 0;
    if (blockIdx.x == 0 && threadIdx.x == 0) {
        int odd_nonzero = 0;
        for (int k = 0; k < 128; ++k)
            if (raw[2 * k + 1] != 0) odd_nonzero = 1;
        *flag = odd_nonzero ? 0 : 1;  // 1 => int64 layout
    }
}

// ---------------------------------------------------------------------------
// conv_hist + wconv fused: blocks [0, ebC) convert edge_index + histogram;
// blocks [ebC, ebC+256) convert the 4 weight matrices to bf16.
// ---------------------------------------------------------------------------
__global__ void conv_hist_wconv_kernel(
    const void* __restrict__ raw, int E, const int* __restrict__ flag,
    int* __restrict__ out, int* __restrict__ deg, int ebC,
    const float* __restrict__ W0, const float* __restrict__ W1,
    const float* __restrict__ W2, const float* __restrict__ W3,
    short* __restrict__ WB)
{
    int b = blockIdx.x;
    if (b < ebC) {
        int i = b * TPB + threadIdx.x;
        if (i >= 2 * E) return;
        int v;
        if (*flag) v = (int)((const long long*)raw)[i];
        else       v = ((const int*)raw)[i];
        out[i] = v;
        if (i < E) atomicAdd(&deg[v], 1);
    } else {
        int i = (b - ebC) * TPB + threadIdx.x;   // 0..65535
        if (i >= 65536) return;
        const float* W = (i < 16384) ? W0 : (i < 32768) ? W1 : (i < 49152) ? W2 : W3;
        WB[i] = f2bf(W[i & 16383]);
    }
}

// ---------------------------------------------------------------------------
// CSR scan chain.
// ---------------------------------------------------------------------------
__global__ void scan1_kernel(const int* __restrict__ deg, int n,
                             int* __restrict__ rowstart, int* __restrict__ bsum)
{
    __shared__ int sm[TPB];
    int t = threadIdx.x;
    int gid = blockIdx.x * TPB + t;
    int v = (gid < n) ? deg[gid] : 0;
    sm[t] = v;
    __syncthreads();
    for (int off = 1; off < TPB; off <<= 1) {
        int x = (t >= off) ? sm[t - off] : 0;
        __syncthreads();
        sm[t] += x;
        __syncthreads();
    }
    if (gid < n) rowstart[gid] = sm[t] - v;
    if (t == TPB - 1) bsum[blockIdx.x] = sm[t];
}

__global__ void scan2_kernel(int* __restrict__ bsum, int nb)
{
    __shared__ int sm[512];
    int t = threadIdx.x;
    int v = (t < nb) ? bsum[t] : 0;
    sm[t] = v;
    __syncthreads();
    for (int off = 1; off < 512; off <<= 1) {
        int x = (t >= off) ? sm[t - off] : 0;
        __syncthreads();
        sm[t] += x;
        __syncthreads();
    }
    if (t < nb) bsum[t] = sm[t] - v;
}

__global__ void scan3_kernel(int* __restrict__ rowstart, int* __restrict__ cursor,
                             int n, int E, const int* __restrict__ bsum)
{
    int gid = blockIdx.x * TPB + threadIdx.x;
    if (gid < n) {
        int v = rowstart[gid] + bsum[blockIdx.x];
        rowstart[gid] = v;
        cursor[gid] = v;
    }
    if (gid == 0) rowstart[n] = E;
}

// Bin edges by destination: ecol[p] = source col, erow[p] = dest row.
__global__ void fill_kernel(const int* __restrict__ ei, int E,
                            int* __restrict__ cursor,
                            int* __restrict__ ecol, int* __restrict__ erow)
{
    int e = blockIdx.x * TPB + threadIdx.x;
    if (e >= E) return;
    int r = ei[e];
    int pos = atomicAdd(&cursor[r], 1);
    ecol[pos] = ei[E + e];
    erow[pos] = r;
}

// ---------------------------------------------------------------------------
// EDGE-PARALLEL scores + fused online softmax partials (r14, validated).
// ---------------------------------------------------------------------------
__global__ __launch_bounds__(256) void epar_score_stats_kernel(
    const short* __restrict__ Qb, const short* __restrict__ Kb,
    const int* __restrict__ erow, const int* __restrict__ ecol, int EH,
    float* __restrict__ S, float* __restrict__ mpart, float* __restrict__ zpart)
{
    int t = threadIdx.x;
    int stride = gridDim.x * TPB;
    float m = -3.0e38f, z = 0.f;
    for (int idx = blockIdx.x * TPB + t; idx < EH; idx += stride) {
        int p = idx >> 3, h = idx & 7;
        int r = erow[p], c = ecol[p];
        const short8* q8 = (const short8*)(Qb + (size_t)r * 128 + h * 16);
        const short8* k8 = (const short8*)(Kb + (size_t)c * 128 + h * 16);
        short8 q0 = q8[0], q1 = q8[1], k0 = k8[0], k1 = k8[1];
        float dot = 0.f;
        #pragma unroll
        for (int i = 0; i < 8; ++i) {
            dot += bf2f(q0[i]) * bf2f(k0[i]);
            dot += bf2f(q1[i]) * bf2f(k1[i]);
        }
        float s = dot * 0.25f;   // 1/sqrt(16)
        S[idx] = s;
        float M = fmaxf(m, s);
        z = z * __expf(m - M) + __expf(s - M);
        m = M;
    }
    __shared__ float sm[TPB], sz[TPB];
    sm[t] = m; sz[t] = z;
    __syncthreads();
    for (int off = 128; off >= 8; off >>= 1) {
        if (t < off) {
            float m2 = sm[t + off], z2 = sz[t + off];
            float M = fmaxf(sm[t], m2);
            sz[t] = sz[t] * __expf(sm[t] - M) + z2 * __expf(m2 - M);
            sm[t] = M;
        }
        __syncthreads();
    }
    if (t < 8) {
        mpart[blockIdx.x * 8 + t] = sm[t];
        zpart[blockIdx.x * 8 + t] = sz[t];
    }
}

// One block: combine nb per-block partials -> MZ[h] (max), MZ[8+h] (Z).
__global__ void stats_reduce_kernel(const float* __restrict__ mpart,
                                    const float* __restrict__ zpart,
                                    int nb, float* __restrict__ MZ)
{
    int t = threadIdx.x;
    int h = t & 7, chunk = t >> 3;   // 32 chunks
    float m = -3.0e38f, z = 0.f;
    for (int i = chunk; i < nb; i += 32) {
        float m2 = mpart[i * 8 + h], z2 = zpart[i * 8 + h];
        float M = fmaxf(m, m2);
        z = z * __expf(m - M) + z2 * __expf(m2 - M);
        m = M;
    }
    __shared__ float sm[TPB], sz[TPB];
    sm[t] = m; sz[t] = z;
    __syncthreads();
    for (int off = 128; off >= 8; off >>= 1) {
        if (t < off) {
            float m2 = sm[t + off], z2 = sz[t + off];
            float M = fmaxf(sm[t], m2);
            sz[t] = sz[t] * __expf(sm[t] - M) + z2 * __expf(m2 - M);
            sm[t] = M;
        }
        __syncthreads();
    }
    if (t < 8) { MZ[t] = sm[t]; MZ[8 + t] = sz[t]; }
}

// ---------------------------------------------------------------------------
// Gather segment-sum, fused exp/normalize, depth-2 prefetch (r13, validated).
// ---------------------------------------------------------------------------
__global__ __launch_bounds__(256) void gather_kernel(
    const float* __restrict__ S, const short* __restrict__ Vb,
    const int* __restrict__ ecol,
    const int* __restrict__ rowstart,
    const float* __restrict__ MZ, int N,
    short* __restrict__ outb)
{
    int idx = blockIdx.x * TPB + threadIdx.x;
    if (idx >= N * 8) return;
    int node = idx >> 3, h = idx & 7;
    float M = MZ[h];
    float invZ = 1.0f / MZ[8 + h];
    int p0 = rowstart[node], p1 = rowstart[node + 1];

    float a[16];
    #pragma unroll
    for (int i = 0; i < 16; ++i) a[i] = 0.f;

    if (p0 < p1) {
        short8 va0, va1, vb0, vb1;
        float sa, sb;
        {
            const short8* vp = (const short8*)(Vb + (size_t)ecol[p0] * 128 + h * 16);
            va0 = vp[0]; va1 = vp[1];
            sa = S[(size_t)p0 * 8 + h];
        }
        if (p0 + 1 < p1) {
            const short8* vp = (const short8*)(Vb + (size_t)ecol[p0+1] * 128 + h * 16);
            vb0 = vp[0]; vb1 = vp[1];
            sb = S[(size_t)(p0+1) * 8 + h];
        } else { vb0 = va0; vb1 = va1; sb = sa; }

        for (int p = p0; p < p1; ++p) {
            short8 vc0 = vb0, vc1 = vb1;
            float sc = sb;
            if (p + 2 < p1) {
                const short8* vp = (const short8*)(Vb + (size_t)ecol[p+2] * 128 + h * 16);
                vc0 = vp[0]; vc1 = vp[1];
                sc = S[(size_t)(p+2) * 8 + h];
            }
            float w = __expf(sa - M) * invZ;
            #pragma unroll
            for (int i = 0; i < 8; ++i) {
                a[i]     += w * bf2f(va0[i]);
                a[8 + i] += w * bf2f(va1[i]);
            }
            va0 = vb0; va1 = vb1; vb0 = vc0; vb1 = vc1;
            sa = sb; sb = sc;
        }
    }
    short8 o0, o1;
    #pragma unroll
    for (int i = 0; i < 8; ++i) { o0[i] = f2bf(a[i]); o1[i] = f2bf(a[8 + i]); }
    short8* ob = (short8*)(outb + (size_t)node * 128 + h * 16);
    ob[0] = o0; ob[1] = o1;
}

// ---------------------------------------------------------------------------
extern "C" void kernel_launch(void* const* d_in, const int* in_sizes, int n_in,
                              void* d_out, int out_size, void* d_ws, size_t ws_size,
                              hipStream_t stream)
{
    const float* feat = (const float*)d_in[0];
    const void*  eraw = d_in[1];
    const float* Wq = (const float*)d_in[2];
    const float* bq = (const float*)d_in[3];
    const float* Wk = (const float*)d_in[4];
    const float* bk = (const float*)d_in[5];
    const float* Wv = (const float*)d_in[6];
    const float* bv = (const float*)d_in[7];
    const float* Wo = (const float*)d_in[8];
    const float* bo = (const float*)d_in[9];

    const int N = in_sizes[0] / 128;
    const int E = in_sizes[1] / 2;
    const size_t NC = (size_t)N * 128;
    const int EH = E * 8;
    const int gbN = (N * 8 + TPB - 1) / TPB;   // node-head grid (gather)
    const int EG  = 2500;                      // edge-stats grid (grid-stride)

    // Workspace layout
    short* Qb   = (short*)d_ws;            // [N][128] bf16 (Q,K,V contiguous)
    short* Kb   = Qb + NC;
    short* Vb   = Kb + NC;
    short* ACCb = Vb + NC;                 // [N][128] bf16
    float* S    = (float*)(ACCb + NC);     // [E*8] scores, CSR order
    int*   EI   = (int*)(S + EH);          // int32 indices, 2*E
    short* WB   = (short*)(EI + 2 * E);    // 4 x 16384 bf16 weights
    float* mpart = (float*)(WB + 65536);   // [EG][8]
    float* zpart = mpart + (size_t)EG * 8;
    float* MZ    = zpart + (size_t)EG * 8; // 16: M[8], Z[8]
    int*   flag  = (int*)(MZ + 16);
    int* deg      = flag + 16;             // N
    int* rowstart = deg + N;               // N+1
    int* cursor   = rowstart + N + 1;      // N
    int* bsum     = cursor + N;            // 512
    int* ecol     = bsum + 512;            // E (binned source cols)
    int* erow     = ecol + E;              // E (binned dest rows)

    const int nbS = (N + TPB - 1) / TPB;
    const int ebE = (E + TPB - 1) / TPB;
    const int ebC = (2 * E + TPB - 1) / TPB;

    // --- CSR build (independent of GEMMs) ---
    init_kernel<<<nbS, TPB, 0, stream>>>(deg, N, (const int*)eraw, flag);
    conv_hist_wconv_kernel<<<ebC + 256, TPB, 0, stream>>>(
        eraw, E, flag, EI, deg, ebC, Wq, Wk, Wv, Wo, WB);
    scan1_kernel<<<nbS, TPB, 0, stream>>>(deg, N, rowstart, bsum);
    scan2_kernel<<<1, 512, 0, stream>>>(bsum, nbS);
    scan3_kernel<<<nbS, TPB, 0, stream>>>(rowstart, cursor, N, E, bsum);
    fill_kernel<<<ebE, TPB, 0, stream>>>(EI, E, cursor, ecol, erow);

    // --- Projections ---
    const int gb = (N + 127) / 128;                 // X tiles
    const int qkvgrid = 8 * 3 * ((gb + 7) / 8);     // XCD-co-located mapping
    gemm_qkv_kernel<<<qkvgrid, TPB, 0, stream>>>(feat, N, gb, WB, bq, bk, bv, Qb, NC);

    // --- Scores + softmax stats (edge-parallel, CSR order) ---
    epar_score_stats_kernel<<<EG, TPB, 0, stream>>>(Qb, Kb, erow, ecol, EH,
                                                    S, mpart, zpart);
    stats_reduce_kernel<<<1, TPB, 0, stream>>>(mpart, zpart, EG, MZ);

    // --- Gather segment-sum with fused exp/normalize -> bf16 ACC ---
    gather_kernel<<<gbN, TPB, 0, stream>>>(S, Vb, ecol, rowstart, MZ, N, ACCb);

    // --- Output projection (bf16 in, fp32 out) ---
    gemm_out_kernel<<<gb, TPB, 0, stream>>>(ACCb, N, WB + 3 * 16384, bo, (float*)d_out);
}